// Round 3
// baseline (677.135 us; speedup 1.0000x reference)
//
#include <hip/hip_runtime.h>
#include <stdint.h>

#define Hh   32
#define Ss   2048
#define Dd   2048
#define DHd  64
#define Mtok 4096   // B*S
#define MiB  (1u << 20)

typedef unsigned short u16;
typedef u16   u16x4  __attribute__((ext_vector_type(4)));
typedef u16   u16x8  __attribute__((ext_vector_type(8)));
typedef short bf16x8 __attribute__((ext_vector_type(8)));
typedef float f32x4  __attribute__((ext_vector_type(4)));

__device__ __forceinline__ u16 f2bf(float f) {
    union { float f; uint32_t u; } v; v.f = f;
    uint32_t r = v.u + 0x7fffu + ((v.u >> 16) & 1u);   // RNE
    return (u16)(r >> 16);
}
__device__ __forceinline__ void gld_lds16(const void* g, void* l) {
    __builtin_amdgcn_global_load_lds(
        (const __attribute__((address_space(1))) uint32_t*)g,
        (__attribute__((address_space(3))) uint32_t*)l,
        16, 0, 0);
}

// ---------------- fp32 -> bf16 convert ----------------
__global__ void cvt_bf16(const float* __restrict__ src, u16* __restrict__ dst, int n)
{
    const int i = (blockIdx.x * 256 + threadIdx.x) * 8;
    if (i + 8 > n) return;
    f32x4 a = *(const f32x4*)(src + i);
    f32x4 b = *(const f32x4*)(src + i + 4);
    u16x8 o;
    o[0] = f2bf(a[0]); o[1] = f2bf(a[1]); o[2] = f2bf(a[2]); o[3] = f2bf(a[3]);
    o[4] = f2bf(b[0]); o[5] = f2bf(b[1]); o[6] = f2bf(b[2]); o[7] = f2bf(b[3]);
    *(u16x8*)(dst + i) = o;
}

// ---------------- GEMM core: C[128x128] += A[128xK] * W[128xK]^T (both K-major bf16) ----------------
__device__ __forceinline__ void gemm_core(const u16* __restrict__ Ap, const u16* __restrict__ Wp,
                                          u16* As, u16* Bs, f32x4 acc[4][4])
{
    const int tid = threadIdx.x, wid = tid >> 6, lane = tid & 63;
    const int l15 = lane & 15, lg = lane >> 4;
    const int wr = wid >> 1, wc = wid & 1;

    for (int kt = 0; kt < Dd; kt += 64) {
#pragma unroll
        for (int c = 0; c < 4; ++c) {
            const int chunk = c * 4 + wid;          // wave-uniform
            const int eoff  = chunk * 512;          // elem offset of 1KB LDS chunk
            const int le    = eoff + lane * 8;      // this lane's element
            const int row = le >> 6, col = le & 63; // [128][64] tile
            gld_lds16(Ap + (size_t)row * Dd + kt + col, As + eoff);
            gld_lds16(Wp + (size_t)row * Dd + kt + col, Bs + eoff);
        }
        __syncthreads();
#pragma unroll
        for (int ks = 0; ks < 2; ++ks) {
            bf16x8 af[4], bw[4];
#pragma unroll
            for (int i = 0; i < 4; ++i)
                af[i] = *(const bf16x8*)(As + (wr * 64 + i * 16 + l15) * 64 + ks * 32 + lg * 8);
#pragma unroll
            for (int i = 0; i < 4; ++i)
                bw[i] = *(const bf16x8*)(Bs + (wc * 64 + i * 16 + l15) * 64 + ks * 32 + lg * 8);
#pragma unroll
            for (int mi = 0; mi < 4; ++mi)
#pragma unroll
                for (int ni = 0; ni < 4; ++ni)
                    acc[mi][ni] = __builtin_amdgcn_mfma_f32_16x16x32_bf16(af[mi], bw[ni], acc[mi][ni], 0, 0, 0);
        }
        __syncthreads();
    }
}

// ---------------- fused QKV projection ----------------
__global__ __launch_bounds__(256) void gemm_qkv(
    const u16* __restrict__ X,
    const u16* __restrict__ Wq, const u16* __restrict__ Wk, const u16* __restrict__ Wv,
    const float* __restrict__ Bq, const float* __restrict__ Bk, const float* __restrict__ Bv,
    u16* __restrict__ Qo, u16* __restrict__ Ko, u16* __restrict__ Vo)
{
    __shared__ __align__(16) u16 As[128 * 64];
    __shared__ __align__(16) u16 Bs[128 * 64];
    const int z = blockIdx.z;
    const u16*   W   = (z == 0) ? Wq : ((z == 1) ? Wk : Wv);
    const float* Bi  = (z == 0) ? Bq : ((z == 1) ? Bk : Bv);
    u16*         Out = (z == 0) ? Qo : ((z == 1) ? Ko : Vo);
    const float scale = (z == 0) ? 0.125f : 1.0f;   // DH^-0.5 on Q (post-bias, like reference)

    const int m0 = blockIdx.x * 128, n0 = blockIdx.y * 128;
    f32x4 acc[4][4] = {};
    gemm_core(X + (size_t)m0 * Dd, W + (size_t)n0 * Dd, As, Bs, acc);

    const int tid = threadIdx.x, wid = tid >> 6, lane = tid & 63;
    const int l15 = lane & 15, lg = lane >> 4;
    const int wr = wid >> 1, wc = wid & 1;
#pragma unroll
    for (int ni = 0; ni < 4; ++ni) {
        const int n = n0 + wc * 64 + ni * 16 + l15;
        const float bv = Bi[n];
        const int h = n >> 6, dh = n & 63;
#pragma unroll
        for (int mi = 0; mi < 4; ++mi) {
#pragma unroll
            for (int r = 0; r < 4; ++r) {
                const int m = m0 + wr * 64 + mi * 16 + lg * 4 + r;
                const int b = m >> 11, s = m & 2047;
                Out[(((size_t)b * Hh + h) * Ss + s) * DHd + dh] = f2bf((acc[mi][ni][r] + bv) * scale);
            }
        }
    }
}

// ---------------- output projection (fp32 out, per harness contract) ----------------
__global__ __launch_bounds__(256) void gemm_oproj(
    const u16* __restrict__ A, const u16* __restrict__ W,
    const float* __restrict__ Bi, float* __restrict__ Out)
{
    __shared__ __align__(16) u16 As[128 * 64];
    __shared__ __align__(16) u16 Bs[128 * 64];
    const int m0 = blockIdx.x * 128, n0 = blockIdx.y * 128;
    f32x4 acc[4][4] = {};
    gemm_core(A + (size_t)m0 * Dd, W + (size_t)n0 * Dd, As, Bs, acc);

    const int tid = threadIdx.x, wid = tid >> 6, lane = tid & 63;
    const int l15 = lane & 15, lg = lane >> 4;
    const int wr = wid >> 1, wc = wid & 1;
#pragma unroll
    for (int ni = 0; ni < 4; ++ni) {
        const int n = n0 + wc * 64 + ni * 16 + l15;
        const float bv = Bi[n];
#pragma unroll
        for (int mi = 0; mi < 4; ++mi) {
#pragma unroll
            for (int r = 0; r < 4; ++r) {
                const int m = m0 + wr * 64 + mi * 16 + lg * 4 + r;
                Out[(size_t)m * Dd + n] = acc[mi][ni][r] + bv;
            }
        }
    }
}

// ---------------- V transpose: [BH][S][DH] -> [BH][DH][S] ----------------
__global__ void transpose_v(const u16* __restrict__ Vsrc, u16* __restrict__ Vdst)
{
    __shared__ __align__(16) u16 t[64 * 68];   // pad stride 68 elems
    const int bh = blockIdx.y, s0 = blockIdx.x * 64;
    const int tid = threadIdx.x;
    {
        const int r = tid >> 2, cq = (tid & 3) * 16;
        const u16* src = Vsrc + ((size_t)bh * Ss + s0 + r) * DHd;
#pragma unroll
        for (int j = 0; j < 4; ++j) {
            u16x4 v = *(const u16x4*)(src + cq + j * 4);
            *(u16x4*)&t[r * 68 + cq + j * 4] = v;
        }
    }
    __syncthreads();
    {
        const int d = tid >> 2, sq = (tid & 3) * 16;
        u16* dst = Vdst + ((size_t)bh * DHd + d) * Ss + s0;
#pragma unroll
        for (int j = 0; j < 4; ++j) {
            u16x4 v;
            v.x = t[(sq + j * 4 + 0) * 68 + d];
            v.y = t[(sq + j * 4 + 1) * 68 + d];
            v.z = t[(sq + j * 4 + 2) * 68 + d];
            v.w = t[(sq + j * 4 + 3) * 68 + d];
            *(u16x4*)(dst + sq + j * 4) = v;
        }
    }
}

// ---------------- flash attention (causal) ----------------
// 4 independent waves/block; wave handles 16 q-rows; KV tiles of 32.
__global__ __launch_bounds__(256) void attn(
    const u16* __restrict__ Qb, const u16* __restrict__ Kb,
    const u16* __restrict__ Vt, u16* __restrict__ Ob)
{
    __shared__ __align__(16) u16 Pl[4][16 * 32];
    const int bh = blockIdx.y;
    const int b = bh >> 5, h = bh & 31;
    const int wid = threadIdx.x >> 6, lane = threadIdx.x & 63;
    const int l15 = lane & 15, lg = lane >> 4;
    const int q0 = blockIdx.x * 64 + wid * 16;
    u16* P = Pl[wid];

    const u16* Qp = Qb + ((size_t)bh * Ss + q0) * DHd;
    const u16* Kp = Kb + (size_t)bh * Ss * DHd;
    const u16* Vp = Vt + (size_t)bh * DHd * Ss;

    bf16x8 aq[2];
#pragma unroll
    for (int kf = 0; kf < 2; ++kf)
        aq[kf] = *(const bf16x8*)(Qp + (size_t)l15 * DHd + kf * 32 + lg * 8);

    f32x4 o[4] = {};
    float mi[4] = { -3e38f, -3e38f, -3e38f, -3e38f };
    float li[4] = { 0.f, 0.f, 0.f, 0.f };

    const int ntiles = (q0 + 16 + 31) >> 5;
    for (int j = 0; j < ntiles; ++j) {
        const int kv0 = j * 32;
        f32x4 s[2] = {};
#pragma unroll
        for (int nb = 0; nb < 2; ++nb)
#pragma unroll
            for (int kf = 0; kf < 2; ++kf) {
                bf16x8 bk = *(const bf16x8*)(Kp + (size_t)(kv0 + nb * 16 + l15) * DHd + kf * 32 + lg * 8);
                s[nb] = __builtin_amdgcn_mfma_f32_16x16x32_bf16(aq[kf], bk, s[nb], 0, 0, 0);
            }
        if (kv0 + 31 > q0) {   // partial (diagonal) tile: mask kv > q
#pragma unroll
            for (int nb = 0; nb < 2; ++nb)
#pragma unroll
                for (int r = 0; r < 4; ++r) {
                    const int kv = kv0 + nb * 16 + l15;
                    const int q  = q0 + lg * 4 + r;
                    if (kv > q) s[nb][r] = -3e38f;
                }
        }
        float pm[4];
#pragma unroll
        for (int r = 0; r < 4; ++r) pm[r] = fmaxf(s[0][r], s[1][r]);
#pragma unroll
        for (int d = 1; d < 16; d <<= 1)
#pragma unroll
            for (int r = 0; r < 4; ++r) pm[r] = fmaxf(pm[r], __shfl_xor(pm[r], d, 64));

        float al[4];
#pragma unroll
        for (int r = 0; r < 4; ++r) {
            const float mn = fmaxf(mi[r], pm[r]);
            al[r] = __expf(mi[r] - mn);
            mi[r] = mn;
        }
        float p[2][4], rs[4];
#pragma unroll
        for (int nb = 0; nb < 2; ++nb)
#pragma unroll
            for (int r = 0; r < 4; ++r) p[nb][r] = __expf(s[nb][r] - mi[r]);
#pragma unroll
        for (int r = 0; r < 4; ++r) rs[r] = p[0][r] + p[1][r];
#pragma unroll
        for (int d = 1; d < 16; d <<= 1)
#pragma unroll
            for (int r = 0; r < 4; ++r) rs[r] += __shfl_xor(rs[r], d, 64);
#pragma unroll
        for (int r = 0; r < 4; ++r) li[r] = li[r] * al[r] + rs[r];
#pragma unroll
        for (int nb = 0; nb < 4; ++nb)
#pragma unroll
            for (int r = 0; r < 4; ++r) o[nb][r] *= al[r];

        // P -> LDS (C-layout) then re-read as MFMA A-operand layout
#pragma unroll
        for (int nb = 0; nb < 2; ++nb)
#pragma unroll
            for (int r = 0; r < 4; ++r)
                P[(lg * 4 + r) * 32 + nb * 16 + l15] = f2bf(p[nb][r]);
        bf16x8 pa = *(const bf16x8*)(P + l15 * 32 + lg * 8);
#pragma unroll
        for (int nb = 0; nb < 4; ++nb) {
            bf16x8 bv = *(const bf16x8*)(Vp + (size_t)(nb * 16 + l15) * Ss + kv0 + lg * 8);
            o[nb] = __builtin_amdgcn_mfma_f32_16x16x32_bf16(pa, bv, o[nb], 0, 0, 0);
        }
    }

#pragma unroll
    for (int nb = 0; nb < 4; ++nb)
#pragma unroll
        for (int r = 0; r < 4; ++r) {
            const float v = o[nb][r] / li[r];
            const int q = q0 + lg * 4 + r, d = nb * 16 + l15;
            Ob[((size_t)b * Ss + q) * Dd + h * DHd + d] = f2bf(v);
        }
}

extern "C" void kernel_launch(void* const* d_in, const int* in_sizes, int n_in,
                              void* d_out, int out_size, void* d_ws, size_t ws_size,
                              hipStream_t stream)
{
    (void)in_sizes; (void)n_in; (void)out_size; (void)ws_size;
    // fp32 device inputs and fp32 output (reference dtypes); bf16 internal compute
    const float* x  = (const float*)d_in[0];
    // d_in[1] = mask: causal, implemented directly
    const float* qw = (const float*)d_in[2];
    const float* qb = (const float*)d_in[3];
    const float* kw = (const float*)d_in[4];
    const float* kb = (const float*)d_in[5];
    const float* vw = (const float*)d_in[6];
    const float* vb = (const float*)d_in[7];
    const float* ow = (const float*)d_in[8];
    const float* obias = (const float*)d_in[9];

    uint8_t* ws = (uint8_t*)d_ws;
    u16* Xb  = (u16*)(ws);                 // 16 MiB [Mtok][Dd]
    u16* Wqb = (u16*)(ws + 16 * MiB);      //  8 MiB [Dd][Dd] (row = out feature)
    u16* Wkb = (u16*)(ws + 24 * MiB);
    u16* Wvb = (u16*)(ws + 32 * MiB);
    u16* Wob = (u16*)(ws + 40 * MiB);
    u16* Qb  = (u16*)(ws + 48 * MiB);      // 16 MiB [BH][S][DH]
    u16* Kb  = (u16*)(ws + 64 * MiB);      // 16 MiB
    u16* Vb  = (u16*)(ws + 80 * MiB);      // 16 MiB
    u16* Vt  = Xb;                         // Xb dead after QKV gemms; [BH][DH][S]
    u16* Ob  = Vb;                         // Vb dead after transpose; attn out

    const int nX = Mtok * Dd;              // 8,388,608
    const int nW = Dd * Dd;                // 4,194,304
    dim3 blk(256);
    cvt_bf16<<<nX / 2048, blk, 0, stream>>>(x,  Xb,  nX);
    cvt_bf16<<<nW / 2048, blk, 0, stream>>>(qw, Wqb, nW);
    cvt_bf16<<<nW / 2048, blk, 0, stream>>>(kw, Wkb, nW);
    cvt_bf16<<<nW / 2048, blk, 0, stream>>>(vw, Wvb, nW);
    cvt_bf16<<<nW / 2048, blk, 0, stream>>>(ow, Wob, nW);

    gemm_qkv<<<dim3(Mtok / 128, Dd / 128, 3), blk, 0, stream>>>(
        Xb, Wqb, Wkb, Wvb, qb, kb, vb, Qb, Kb, Vb);
    transpose_v<<<dim3(Ss / 64, 64), blk, 0, stream>>>(Vb, Vt);
    attn<<<dim3(Ss / 64, 64), blk, 0, stream>>>(Qb, Kb, Vt, Ob);
    gemm_oproj<<<dim3(Mtok / 128, Dd / 128, 1), blk, 0, stream>>>(
        Ob, Wob, obias, (float*)d_out);
}

// Round 4
// 438.759 us; speedup vs baseline: 1.5433x; 1.5433x over previous
//
#include <hip/hip_runtime.h>
#include <stdint.h>

#define Hh   32
#define Ss   2048
#define Dd   2048
#define DHd  64
#define Mtok 4096   // B*S
#define MiB  (1u << 20)

typedef unsigned short u16;
typedef u16   u16x4  __attribute__((ext_vector_type(4)));
typedef u16   u16x8  __attribute__((ext_vector_type(8)));
typedef short bf16x8 __attribute__((ext_vector_type(8)));
typedef float f32x4  __attribute__((ext_vector_type(4)));

__device__ __forceinline__ u16 f2bf(float f) {
    union { float f; uint32_t u; } v; v.f = f;
    uint32_t r = v.u + 0x7fffu + ((v.u >> 16) & 1u);   // RNE
    return (u16)(r >> 16);
}
__device__ __forceinline__ void gld_lds16(const void* g, void* l) {
    __builtin_amdgcn_global_load_lds(
        (const __attribute__((address_space(1))) uint32_t*)g,
        (__attribute__((address_space(3))) uint32_t*)l,
        16, 0, 0);
}

// ---------------- fp32 -> bf16 convert ----------------
__global__ void cvt_bf16(const float* __restrict__ src, u16* __restrict__ dst, int n)
{
    const int i = (blockIdx.x * 256 + threadIdx.x) * 8;
    if (i + 8 > n) return;
    f32x4 a = *(const f32x4*)(src + i);
    f32x4 b = *(const f32x4*)(src + i + 4);
    u16x8 o;
    o[0] = f2bf(a[0]); o[1] = f2bf(a[1]); o[2] = f2bf(a[2]); o[3] = f2bf(a[3]);
    o[4] = f2bf(b[0]); o[5] = f2bf(b[1]); o[6] = f2bf(b[2]); o[7] = f2bf(b[3]);
    *(u16x8*)(dst + i) = o;
}

// ---------------- GEMM core: C[128x128] += A[128xK] * W[128xK]^T (both K-major bf16) ----------------
__device__ __forceinline__ void gemm_core(const u16* __restrict__ Ap, const u16* __restrict__ Wp,
                                          u16* As, u16* Bs, f32x4 acc[4][4])
{
    const int tid = threadIdx.x, wid = tid >> 6, lane = tid & 63;
    const int l15 = lane & 15, lg = lane >> 4;
    const int wr = wid >> 1, wc = wid & 1;

    for (int kt = 0; kt < Dd; kt += 64) {
#pragma unroll
        for (int c = 0; c < 4; ++c) {
            const int chunk = c * 4 + wid;          // wave-uniform
            const int eoff  = chunk * 512;          // elem offset of 1KB LDS chunk
            const int le    = eoff + lane * 8;      // this lane's element
            const int row = le >> 6, col = le & 63; // [128][64] tile
            gld_lds16(Ap + (size_t)row * Dd + kt + col, As + eoff);
            gld_lds16(Wp + (size_t)row * Dd + kt + col, Bs + eoff);
        }
        __syncthreads();
#pragma unroll
        for (int ks = 0; ks < 2; ++ks) {
            bf16x8 af[4], bw[4];
#pragma unroll
            for (int i = 0; i < 4; ++i)
                af[i] = *(const bf16x8*)(As + (wr * 64 + i * 16 + l15) * 64 + ks * 32 + lg * 8);
#pragma unroll
            for (int i = 0; i < 4; ++i)
                bw[i] = *(const bf16x8*)(Bs + (wc * 64 + i * 16 + l15) * 64 + ks * 32 + lg * 8);
#pragma unroll
            for (int mi = 0; mi < 4; ++mi)
#pragma unroll
                for (int ni = 0; ni < 4; ++ni)
                    acc[mi][ni] = __builtin_amdgcn_mfma_f32_16x16x32_bf16(af[mi], bw[ni], acc[mi][ni], 0, 0, 0);
        }
        __syncthreads();
    }
}

// ---------------- fused QKV projection ----------------
__global__ __launch_bounds__(256) void gemm_qkv(
    const u16* __restrict__ X,
    const u16* __restrict__ Wq, const u16* __restrict__ Wk, const u16* __restrict__ Wv,
    const float* __restrict__ Bq, const float* __restrict__ Bk, const float* __restrict__ Bv,
    u16* __restrict__ Qo, u16* __restrict__ Ko, u16* __restrict__ Vo)
{
    __shared__ __align__(16) u16 As[128 * 64];
    __shared__ __align__(16) u16 Bs[128 * 64];
    const int z = blockIdx.z;
    const u16*   W   = (z == 0) ? Wq : ((z == 1) ? Wk : Wv);
    const float* Bi  = (z == 0) ? Bq : ((z == 1) ? Bk : Bv);
    u16*         Out = (z == 0) ? Qo : ((z == 1) ? Ko : Vo);
    const float scale = (z == 0) ? 0.125f : 1.0f;   // DH^-0.5 on Q (post-bias, like reference)

    const int m0 = blockIdx.x * 128, n0 = blockIdx.y * 128;
    f32x4 acc[4][4] = {};
    gemm_core(X + (size_t)m0 * Dd, W + (size_t)n0 * Dd, As, Bs, acc);

    const int tid = threadIdx.x, wid = tid >> 6, lane = tid & 63;
    const int l15 = lane & 15, lg = lane >> 4;
    const int wr = wid >> 1, wc = wid & 1;
#pragma unroll
    for (int ni = 0; ni < 4; ++ni) {
        const int n = n0 + wc * 64 + ni * 16 + l15;
        const float bv = Bi[n];
        const int h = n >> 6, dh = n & 63;
#pragma unroll
        for (int mi = 0; mi < 4; ++mi) {
#pragma unroll
            for (int r = 0; r < 4; ++r) {
                const int m = m0 + wr * 64 + mi * 16 + lg * 4 + r;
                const int b = m >> 11, s = m & 2047;
                Out[(((size_t)b * Hh + h) * Ss + s) * DHd + dh] = f2bf((acc[mi][ni][r] + bv) * scale);
            }
        }
    }
}

// ---------------- output projection (fp32 out, per harness contract) ----------------
__global__ __launch_bounds__(256) void gemm_oproj(
    const u16* __restrict__ A, const u16* __restrict__ W,
    const float* __restrict__ Bi, float* __restrict__ Out)
{
    __shared__ __align__(16) u16 As[128 * 64];
    __shared__ __align__(16) u16 Bs[128 * 64];
    const int m0 = blockIdx.x * 128, n0 = blockIdx.y * 128;
    f32x4 acc[4][4] = {};
    gemm_core(A + (size_t)m0 * Dd, W + (size_t)n0 * Dd, As, Bs, acc);

    const int tid = threadIdx.x, wid = tid >> 6, lane = tid & 63;
    const int l15 = lane & 15, lg = lane >> 4;
    const int wr = wid >> 1, wc = wid & 1;
#pragma unroll
    for (int ni = 0; ni < 4; ++ni) {
        const int n = n0 + wc * 64 + ni * 16 + l15;
        const float bv = Bi[n];
#pragma unroll
        for (int mi = 0; mi < 4; ++mi) {
#pragma unroll
            for (int r = 0; r < 4; ++r) {
                const int m = m0 + wr * 64 + mi * 16 + lg * 4 + r;
                Out[(size_t)m * Dd + n] = acc[mi][ni][r] + bv;
            }
        }
    }
}

// ---------------- V transpose: [BH][S][DH] -> [BH][DH][S] ----------------
__global__ void transpose_v(const u16* __restrict__ Vsrc, u16* __restrict__ Vdst)
{
    __shared__ __align__(16) u16 t[64 * 68];   // pad stride 68 elems
    const int bh = blockIdx.y, s0 = blockIdx.x * 64;
    const int tid = threadIdx.x;
    {
        const int r = tid >> 2, cq = (tid & 3) * 16;
        const u16* src = Vsrc + ((size_t)bh * Ss + s0 + r) * DHd;
#pragma unroll
        for (int j = 0; j < 4; ++j) {
            u16x4 v = *(const u16x4*)(src + cq + j * 4);
            *(u16x4*)&t[r * 68 + cq + j * 4] = v;
        }
    }
    __syncthreads();
    {
        const int d = tid >> 2, sq = (tid & 3) * 16;
        u16* dst = Vdst + ((size_t)bh * DHd + d) * Ss + s0;
#pragma unroll
        for (int j = 0; j < 4; ++j) {
            u16x4 v;
            v.x = t[(sq + j * 4 + 0) * 68 + d];
            v.y = t[(sq + j * 4 + 1) * 68 + d];
            v.z = t[(sq + j * 4 + 2) * 68 + d];
            v.w = t[(sq + j * 4 + 3) * 68 + d];
            *(u16x4*)(dst + sq + j * 4) = v;
        }
    }
}

// ---------------- flash attention (causal), block-cooperative ----------------
// 4 waves/block share double-buffered LDS K/V tiles (KVBLK=64, XOR-swizzled);
// each wave owns 16 q-rows. P via padded LDS (72 elems/row).
__device__ __forceinline__ void stage_kv(const u16* __restrict__ Kg, const u16* __restrict__ Vg,
                                         u16* Kl, u16* Vl, int kv0, int tid)
{
    const int w = tid >> 6, lane = tid & 63;
#pragma unroll
    for (int i = 0; i < 2; ++i) {
        const int ub  = i * 256 + w * 64;          // wave-uniform 16B-chunk base
        const int u   = ub + lane;
        const int row = u >> 3;
        const int csrc = ((u & 7) ^ (row & 7)) * 8; // pre-swizzled source col (elems)
        gld_lds16(Kg + (size_t)(kv0 + row) * DHd + csrc, Kl + ub * 8);
        gld_lds16(Vg + (size_t)row * Ss + kv0 + csrc, Vl + ub * 8);
    }
}

__global__ __launch_bounds__(256) void attn(
    const u16* __restrict__ Qb, const u16* __restrict__ Kb,
    const u16* __restrict__ Vt, u16* __restrict__ Ob)
{
    __shared__ __align__(16) u16 Kl[2][4096];
    __shared__ __align__(16) u16 Vl[2][4096];
    __shared__ __align__(16) u16 Pl[4][16 * 72];
    const int bh = blockIdx.y;
    const int b = bh >> 5, h = bh & 31;
    const int tid = threadIdx.x;
    const int wid = tid >> 6, lane = tid & 63;
    const int l15 = lane & 15, lg = lane >> 4;
    const int q0 = blockIdx.x * 64 + wid * 16;
    u16* Pw = Pl[wid];

    const u16* Qp = Qb + ((size_t)bh * Ss + q0) * DHd;
    const u16* Kp = Kb + (size_t)bh * Ss * DHd;
    const u16* Vp = Vt + (size_t)bh * DHd * Ss;

    bf16x8 aq[2];
#pragma unroll
    for (int kf = 0; kf < 2; ++kf)
        aq[kf] = *(const bf16x8*)(Qp + (size_t)l15 * DHd + kf * 32 + lg * 8);

    f32x4 o[4] = {};
    float mi[4] = { -3e38f, -3e38f, -3e38f, -3e38f };
    float li[4] = { 0.f, 0.f, 0.f, 0.f };

    const int nt = blockIdx.x + 1;   // causal: tiles 0..q0_blk/64

    stage_kv(Kp, Vp, Kl[0], Vl[0], 0, tid);
    __syncthreads();

    for (int t = 0; t < nt; ++t) {
        if (t + 1 < nt)
            stage_kv(Kp, Vp, Kl[(t + 1) & 1], Vl[(t + 1) & 1], (t + 1) * 64, tid);
        const u16* Kc = Kl[t & 1];
        const u16* Vc = Vl[t & 1];
        const int kv0 = t * 64;

        // QK^T: s[nb] covers kv = kv0 + nb*16 + l15, q = q0 + lg*4 + r
        f32x4 s[4] = {};
#pragma unroll
        for (int nb = 0; nb < 4; ++nb) {
            const int krow = nb * 16 + l15;
            const char* rb = (const char*)(Kc + krow * 64);
            const int sw = (krow & 7) << 4;
#pragma unroll
            for (int kf = 0; kf < 2; ++kf) {
                bf16x8 bk = *(const bf16x8*)(rb + ((kf * 64 + lg * 16) ^ sw));
                s[nb] = __builtin_amdgcn_mfma_f32_16x16x32_bf16(aq[kf], bk, s[nb], 0, 0, 0);
            }
        }
        if (t == nt - 1) {   // diagonal tile: mask kv > q
#pragma unroll
            for (int nb = 0; nb < 4; ++nb)
#pragma unroll
                for (int r = 0; r < 4; ++r) {
                    const int kv = kv0 + nb * 16 + l15;
                    const int q  = q0 + lg * 4 + r;
                    if (kv > q) s[nb][r] = -3e38f;
                }
        }
        // online softmax (row-reduce across the 16-lane l15 group)
        float pm[4];
#pragma unroll
        for (int r = 0; r < 4; ++r)
            pm[r] = fmaxf(fmaxf(s[0][r], s[1][r]), fmaxf(s[2][r], s[3][r]));
#pragma unroll
        for (int d = 1; d < 16; d <<= 1)
#pragma unroll
            for (int r = 0; r < 4; ++r) pm[r] = fmaxf(pm[r], __shfl_xor(pm[r], d, 64));
        float al[4], rs[4];
#pragma unroll
        for (int r = 0; r < 4; ++r) {
            const float mn = fmaxf(mi[r], pm[r]);
            al[r] = __expf(mi[r] - mn);
            mi[r] = mn;
            rs[r] = 0.f;
        }
#pragma unroll
        for (int nb = 0; nb < 4; ++nb)
#pragma unroll
            for (int r = 0; r < 4; ++r) {
                const float pv = __expf(s[nb][r] - mi[r]);
                rs[r] += pv;
                Pw[(lg * 4 + r) * 72 + nb * 16 + l15] = f2bf(pv);
            }
#pragma unroll
        for (int d = 1; d < 16; d <<= 1)
#pragma unroll
            for (int r = 0; r < 4; ++r) rs[r] += __shfl_xor(rs[r], d, 64);
#pragma unroll
        for (int r = 0; r < 4; ++r) li[r] = li[r] * al[r] + rs[r];
#pragma unroll
        for (int nb = 0; nb < 4; ++nb)
#pragma unroll
            for (int r = 0; r < 4; ++r) o[nb][r] *= al[r];

        // PV: o[nb] covers d = nb*16 + l15
        bf16x8 pa[2];
#pragma unroll
        for (int ks = 0; ks < 2; ++ks)
            pa[ks] = *(const bf16x8*)(Pw + l15 * 72 + ks * 32 + lg * 8);
#pragma unroll
        for (int nb = 0; nb < 4; ++nb) {
            const int vrow = nb * 16 + l15;
            const char* rb = (const char*)(Vc + vrow * 64);
            const int sw = (vrow & 7) << 4;
#pragma unroll
            for (int ks = 0; ks < 2; ++ks) {
                bf16x8 bv = *(const bf16x8*)(rb + ((ks * 64 + lg * 16) ^ sw));
                o[nb] = __builtin_amdgcn_mfma_f32_16x16x32_bf16(pa[ks], bv, o[nb], 0, 0, 0);
            }
        }
        __syncthreads();
    }

#pragma unroll
    for (int r = 0; r < 4; ++r) li[r] = 1.0f / li[r];
#pragma unroll
    for (int nb = 0; nb < 4; ++nb)
#pragma unroll
        for (int r = 0; r < 4; ++r) {
            const int q = q0 + lg * 4 + r, d = nb * 16 + l15;
            Ob[((size_t)b * Ss + q) * Dd + h * DHd + d] = f2bf(o[nb][r] * li[r]);
        }
}

extern "C" void kernel_launch(void* const* d_in, const int* in_sizes, int n_in,
                              void* d_out, int out_size, void* d_ws, size_t ws_size,
                              hipStream_t stream)
{
    (void)in_sizes; (void)n_in; (void)out_size; (void)ws_size;
    // fp32 device inputs and fp32 output (reference dtypes); bf16 internal compute
    const float* x  = (const float*)d_in[0];
    // d_in[1] = mask: causal, implemented directly
    const float* qw = (const float*)d_in[2];
    const float* qb = (const float*)d_in[3];
    const float* kw = (const float*)d_in[4];
    const float* kb = (const float*)d_in[5];
    const float* vw = (const float*)d_in[6];
    const float* vb = (const float*)d_in[7];
    const float* ow = (const float*)d_in[8];
    const float* obias = (const float*)d_in[9];

    uint8_t* ws = (uint8_t*)d_ws;
    u16* Xb  = (u16*)(ws);                 // 16 MiB [Mtok][Dd]
    u16* Wqb = (u16*)(ws + 16 * MiB);      //  8 MiB [Dd][Dd] (row = out feature)
    u16* Wkb = (u16*)(ws + 24 * MiB);
    u16* Wvb = (u16*)(ws + 32 * MiB);
    u16* Wob = (u16*)(ws + 40 * MiB);
    u16* Qb  = (u16*)(ws + 48 * MiB);      // 16 MiB [BH][S][DH]
    u16* Kb  = (u16*)(ws + 64 * MiB);      // 16 MiB
    u16* Vb  = (u16*)(ws + 80 * MiB);      // 16 MiB
    u16* Vt  = Xb;                         // Xb dead after QKV gemms; [BH][DH][S]
    u16* Ob  = Vb;                         // Vb dead after transpose; attn out

    const int nX = Mtok * Dd;              // 8,388,608
    const int nW = Dd * Dd;                // 4,194,304
    dim3 blk(256);
    cvt_bf16<<<nX / 2048, blk, 0, stream>>>(x,  Xb,  nX);
    cvt_bf16<<<nW / 2048, blk, 0, stream>>>(qw, Wqb, nW);
    cvt_bf16<<<nW / 2048, blk, 0, stream>>>(kw, Wkb, nW);
    cvt_bf16<<<nW / 2048, blk, 0, stream>>>(vw, Wvb, nW);
    cvt_bf16<<<nW / 2048, blk, 0, stream>>>(ow, Wob, nW);

    gemm_qkv<<<dim3(Mtok / 128, Dd / 128, 3), blk, 0, stream>>>(
        Xb, Wqb, Wkb, Wvb, qb, kb, vb, Qb, Kb, Vb);
    transpose_v<<<dim3(Ss / 64, 64), blk, 0, stream>>>(Vb, Vt);
    attn<<<dim3(Ss / 64, 64), blk, 0, stream>>>(Qb, Kb, Vt, Ob);
    gemm_oproj<<<dim3(Mtok / 128, Dd / 128, 1), blk, 0, stream>>>(
        Ob, Wob, obias, (float*)d_out);
}

// Round 5
// 414.003 us; speedup vs baseline: 1.6356x; 1.0598x over previous
//
#include <hip/hip_runtime.h>
#include <stdint.h>

#define Hh   32
#define Ss   2048
#define Dd   2048
#define DHd  64
#define Mtok 4096   // B*S
#define MiB  (1u << 20)

typedef unsigned short u16;
typedef u16   u16x4  __attribute__((ext_vector_type(4)));
typedef u16   u16x8  __attribute__((ext_vector_type(8)));
typedef short bf16x8 __attribute__((ext_vector_type(8)));
typedef float f32x4  __attribute__((ext_vector_type(4)));

__device__ __forceinline__ u16 f2bf(float f) {
    union { float f; uint32_t u; } v; v.f = f;
    uint32_t r = v.u + 0x7fffu + ((v.u >> 16) & 1u);   // RNE
    return (u16)(r >> 16);
}
__device__ __forceinline__ void gld_lds16(const void* g, void* l) {
    __builtin_amdgcn_global_load_lds(
        (const __attribute__((address_space(1))) uint32_t*)g,
        (__attribute__((address_space(3))) uint32_t*)l,
        16, 0, 0);
}

// ---------------- fp32 -> bf16 convert ----------------
__global__ void cvt_bf16(const float* __restrict__ src, u16* __restrict__ dst, int n)
{
    const int i = (blockIdx.x * 256 + threadIdx.x) * 8;
    if (i + 8 > n) return;
    f32x4 a = *(const f32x4*)(src + i);
    f32x4 b = *(const f32x4*)(src + i + 4);
    u16x8 o;
    o[0] = f2bf(a[0]); o[1] = f2bf(a[1]); o[2] = f2bf(a[2]); o[3] = f2bf(a[3]);
    o[4] = f2bf(b[0]); o[5] = f2bf(b[1]); o[6] = f2bf(b[2]); o[7] = f2bf(b[3]);
    *(u16x8*)(dst + i) = o;
}

// ---------------- GEMM core: C[128x128] += A[128xK] * W[128xK]^T (both K-major bf16) ----------------
__device__ __forceinline__ void gemm_core(const u16* __restrict__ Ap, const u16* __restrict__ Wp,
                                          u16* As, u16* Bs, f32x4 acc[4][4])
{
    const int tid = threadIdx.x, wid = tid >> 6, lane = tid & 63;
    const int l15 = lane & 15, lg = lane >> 4;
    const int wr = wid >> 1, wc = wid & 1;

    for (int kt = 0; kt < Dd; kt += 64) {
#pragma unroll
        for (int c = 0; c < 4; ++c) {
            const int chunk = c * 4 + wid;          // wave-uniform
            const int eoff  = chunk * 512;          // elem offset of 1KB LDS chunk
            const int le    = eoff + lane * 8;      // this lane's element
            const int row = le >> 6, col = le & 63; // [128][64] tile
            gld_lds16(Ap + (size_t)row * Dd + kt + col, As + eoff);
            gld_lds16(Wp + (size_t)row * Dd + kt + col, Bs + eoff);
        }
        __syncthreads();
#pragma unroll
        for (int ks = 0; ks < 2; ++ks) {
            bf16x8 af[4], bw[4];
#pragma unroll
            for (int i = 0; i < 4; ++i)
                af[i] = *(const bf16x8*)(As + (wr * 64 + i * 16 + l15) * 64 + ks * 32 + lg * 8);
#pragma unroll
            for (int i = 0; i < 4; ++i)
                bw[i] = *(const bf16x8*)(Bs + (wc * 64 + i * 16 + l15) * 64 + ks * 32 + lg * 8);
#pragma unroll
            for (int mi = 0; mi < 4; ++mi)
#pragma unroll
                for (int ni = 0; ni < 4; ++ni)
                    acc[mi][ni] = __builtin_amdgcn_mfma_f32_16x16x32_bf16(af[mi], bw[ni], acc[mi][ni], 0, 0, 0);
        }
        __syncthreads();
    }
}

// ---------------- fused QKV projection ----------------
__global__ __launch_bounds__(256) void gemm_qkv(
    const u16* __restrict__ X,
    const u16* __restrict__ Wq, const u16* __restrict__ Wk, const u16* __restrict__ Wv,
    const float* __restrict__ Bq, const float* __restrict__ Bk, const float* __restrict__ Bv,
    u16* __restrict__ Qo, u16* __restrict__ Ko, u16* __restrict__ Vo)
{
    __shared__ __align__(16) u16 As[128 * 64];
    __shared__ __align__(16) u16 Bs[128 * 64];
    const int z = blockIdx.z;
    const u16*   W   = (z == 0) ? Wq : ((z == 1) ? Wk : Wv);
    const float* Bi  = (z == 0) ? Bq : ((z == 1) ? Bk : Bv);
    u16*         Out = (z == 0) ? Qo : ((z == 1) ? Ko : Vo);
    const float scale = (z == 0) ? 0.125f : 1.0f;   // DH^-0.5 on Q (post-bias, like reference)

    const int m0 = blockIdx.x * 128, n0 = blockIdx.y * 128;
    f32x4 acc[4][4] = {};
    gemm_core(X + (size_t)m0 * Dd, W + (size_t)n0 * Dd, As, Bs, acc);

    const int tid = threadIdx.x, wid = tid >> 6, lane = tid & 63;
    const int l15 = lane & 15, lg = lane >> 4;
    const int wr = wid >> 1, wc = wid & 1;
#pragma unroll
    for (int ni = 0; ni < 4; ++ni) {
        const int n = n0 + wc * 64 + ni * 16 + l15;
        const float bv = Bi[n];
        const int h = n >> 6, dh = n & 63;
#pragma unroll
        for (int mi = 0; mi < 4; ++mi) {
#pragma unroll
            for (int r = 0; r < 4; ++r) {
                const int m = m0 + wr * 64 + mi * 16 + lg * 4 + r;
                const int b = m >> 11, s = m & 2047;
                Out[(((size_t)b * Hh + h) * Ss + s) * DHd + dh] = f2bf((acc[mi][ni][r] + bv) * scale);
            }
        }
    }
}

// ---------------- output projection (fp32 out, per harness contract) ----------------
__global__ __launch_bounds__(256) void gemm_oproj(
    const u16* __restrict__ A, const u16* __restrict__ W,
    const float* __restrict__ Bi, float* __restrict__ Out)
{
    __shared__ __align__(16) u16 As[128 * 64];
    __shared__ __align__(16) u16 Bs[128 * 64];
    const int m0 = blockIdx.x * 128, n0 = blockIdx.y * 128;
    f32x4 acc[4][4] = {};
    gemm_core(A + (size_t)m0 * Dd, W + (size_t)n0 * Dd, As, Bs, acc);

    const int tid = threadIdx.x, wid = tid >> 6, lane = tid & 63;
    const int l15 = lane & 15, lg = lane >> 4;
    const int wr = wid >> 1, wc = wid & 1;
#pragma unroll
    for (int ni = 0; ni < 4; ++ni) {
        const int n = n0 + wc * 64 + ni * 16 + l15;
        const float bv = Bi[n];
#pragma unroll
        for (int mi = 0; mi < 4; ++mi) {
#pragma unroll
            for (int r = 0; r < 4; ++r) {
                const int m = m0 + wr * 64 + mi * 16 + lg * 4 + r;
                Out[(size_t)m * Dd + n] = acc[mi][ni][r] + bv;
            }
        }
    }
}

// ---------------- V transpose: [BH][S][DH] -> [BH][DH][S] ----------------
__global__ void transpose_v(const u16* __restrict__ Vsrc, u16* __restrict__ Vdst)
{
    __shared__ __align__(16) u16 t[64 * 68];   // pad stride 68 elems
    const int bh = blockIdx.y, s0 = blockIdx.x * 64;
    const int tid = threadIdx.x;
    {
        const int r = tid >> 2, cq = (tid & 3) * 16;
        const u16* src = Vsrc + ((size_t)bh * Ss + s0 + r) * DHd;
#pragma unroll
        for (int j = 0; j < 4; ++j) {
            u16x4 v = *(const u16x4*)(src + cq + j * 4);
            *(u16x4*)&t[r * 68 + cq + j * 4] = v;
        }
    }
    __syncthreads();
    {
        const int d = tid >> 2, sq = (tid & 3) * 16;
        u16* dst = Vdst + ((size_t)bh * DHd + d) * Ss + s0;
#pragma unroll
        for (int j = 0; j < 4; ++j) {
            u16x4 v;
            v.x = t[(sq + j * 4 + 0) * 68 + d];
            v.y = t[(sq + j * 4 + 1) * 68 + d];
            v.z = t[(sq + j * 4 + 2) * 68 + d];
            v.w = t[(sq + j * 4 + 3) * 68 + d];
            *(u16x4*)(dst + sq + j * 4) = v;
        }
    }
}

// ---------------- flash attention (causal), block-cooperative ----------------
// 8 waves/block (512 thr) share double-buffered LDS K/V tiles (KVBLK=64,
// XOR-swizzled); each wave owns 16 q-rows (QBLK=128). P via padded LDS.
__device__ __forceinline__ void stage_kv(const u16* __restrict__ Kg, const u16* __restrict__ Vg,
                                         u16* Kl, u16* Vl, int kv0, int tid)
{
    // 512 threads x 16B = one full 64x64 bf16 tile per instruction
    const int u    = tid;                         // 16B-chunk id 0..511
    const int row  = u >> 3;                      // 64 rows, 8 chunks each
    const int csrc = ((u & 7) ^ (row & 7)) * 8;   // pre-swizzled source col (elems)
    const int base = (u & ~63) * 8;               // wave-uniform LDS elem base
    gld_lds16(Kg + (size_t)(kv0 + row) * DHd + csrc, Kl + base);
    gld_lds16(Vg + (size_t)row * Ss + kv0 + csrc, Vl + base);
}

__global__ __launch_bounds__(512) void attn(
    const u16* __restrict__ Qb, const u16* __restrict__ Kb,
    const u16* __restrict__ Vt, u16* __restrict__ Ob)
{
    __shared__ __align__(16) u16 Kl[2][4096];
    __shared__ __align__(16) u16 Vl[2][4096];
    __shared__ __align__(16) u16 Pl[8][16 * 72];
    const int bh = blockIdx.y;
    const int b = bh >> 5, h = bh & 31;
    const int tid = threadIdx.x;
    const int wid = tid >> 6, lane = tid & 63;
    const int l15 = lane & 15, lg = lane >> 4;
    const int q0 = blockIdx.x * 128 + wid * 16;
    u16* Pw = Pl[wid];

    const u16* Qp = Qb + ((size_t)bh * Ss + q0) * DHd;
    const u16* Kp = Kb + (size_t)bh * Ss * DHd;
    const u16* Vp = Vt + (size_t)bh * DHd * Ss;

    bf16x8 aq[2];
#pragma unroll
    for (int kf = 0; kf < 2; ++kf)
        aq[kf] = *(const bf16x8*)(Qp + (size_t)l15 * DHd + kf * 32 + lg * 8);

    f32x4 o[4] = {};
    float mi[4] = { -3e38f, -3e38f, -3e38f, -3e38f };
    float li[4] = { 0.f, 0.f, 0.f, 0.f };

    const int nt = 2 * (blockIdx.x + 1);   // causal: kv tiles covering q < (bx+1)*128

    stage_kv(Kp, Vp, Kl[0], Vl[0], 0, tid);
    __syncthreads();

    for (int t = 0; t < nt; ++t) {
        if (t + 1 < nt)
            stage_kv(Kp, Vp, Kl[(t + 1) & 1], Vl[(t + 1) & 1], (t + 1) * 64, tid);
        const u16* Kc = Kl[t & 1];
        const u16* Vc = Vl[t & 1];
        const int kv0 = t * 64;

        // QK^T: s[nb] covers kv = kv0 + nb*16 + l15, q = q0 + lg*4 + r
        f32x4 s[4] = {};
#pragma unroll
        for (int nb = 0; nb < 4; ++nb) {
            const int krow = nb * 16 + l15;
            const char* rb = (const char*)(Kc + krow * 64);
            const int sw = (krow & 7) << 4;
#pragma unroll
            for (int kf = 0; kf < 2; ++kf) {
                bf16x8 bk = *(const bf16x8*)(rb + ((kf * 64 + lg * 16) ^ sw));
                s[nb] = __builtin_amdgcn_mfma_f32_16x16x32_bf16(aq[kf], bk, s[nb], 0, 0, 0);
            }
        }
        if (kv0 + 63 > q0) {   // tile reaches past this wave's diagonal: mask kv > q
#pragma unroll
            for (int nb = 0; nb < 4; ++nb)
#pragma unroll
                for (int r = 0; r < 4; ++r) {
                    const int kv = kv0 + nb * 16 + l15;
                    const int q  = q0 + lg * 4 + r;
                    if (kv > q) s[nb][r] = -3e38f;
                }
        }
        // online softmax (row-reduce across the 16-lane l15 group)
        float pm[4];
#pragma unroll
        for (int r = 0; r < 4; ++r)
            pm[r] = fmaxf(fmaxf(s[0][r], s[1][r]), fmaxf(s[2][r], s[3][r]));
#pragma unroll
        for (int d = 1; d < 16; d <<= 1)
#pragma unroll
            for (int r = 0; r < 4; ++r) pm[r] = fmaxf(pm[r], __shfl_xor(pm[r], d, 64));
        float al[4], rs[4];
#pragma unroll
        for (int r = 0; r < 4; ++r) {
            const float mn = fmaxf(mi[r], pm[r]);
            al[r] = __expf(mi[r] - mn);
            mi[r] = mn;
            rs[r] = 0.f;
        }
#pragma unroll
        for (int nb = 0; nb < 4; ++nb)
#pragma unroll
            for (int r = 0; r < 4; ++r) {
                const float pv = __expf(s[nb][r] - mi[r]);
                rs[r] += pv;
                Pw[(lg * 4 + r) * 72 + nb * 16 + l15] = f2bf(pv);
            }
#pragma unroll
        for (int d = 1; d < 16; d <<= 1)
#pragma unroll
            for (int r = 0; r < 4; ++r) rs[r] += __shfl_xor(rs[r], d, 64);
#pragma unroll
        for (int r = 0; r < 4; ++r) li[r] = li[r] * al[r] + rs[r];
#pragma unroll
        for (int nb = 0; nb < 4; ++nb)
#pragma unroll
            for (int r = 0; r < 4; ++r) o[nb][r] *= al[r];

        // PV: o[nb] covers d = nb*16 + l15
        bf16x8 pa[2];
#pragma unroll
        for (int ks = 0; ks < 2; ++ks)
            pa[ks] = *(const bf16x8*)(Pw + l15 * 72 + ks * 32 + lg * 8);
#pragma unroll
        for (int nb = 0; nb < 4; ++nb) {
            const int vrow = nb * 16 + l15;
            const char* rb = (const char*)(Vc + vrow * 64);
            const int sw = (vrow & 7) << 4;
#pragma unroll
            for (int ks = 0; ks < 2; ++ks) {
                bf16x8 bv = *(const bf16x8*)(rb + ((ks * 64 + lg * 16) ^ sw));
                o[nb] = __builtin_amdgcn_mfma_f32_16x16x32_bf16(pa[ks], bv, o[nb], 0, 0, 0);
            }
        }
        __syncthreads();
    }

#pragma unroll
    for (int r = 0; r < 4; ++r) li[r] = 1.0f / li[r];
#pragma unroll
    for (int nb = 0; nb < 4; ++nb)
#pragma unroll
        for (int r = 0; r < 4; ++r) {
            const int q = q0 + lg * 4 + r, d = nb * 16 + l15;
            Ob[((size_t)b * Ss + q) * Dd + h * DHd + d] = f2bf(o[nb][r] * li[r]);
        }
}

extern "C" void kernel_launch(void* const* d_in, const int* in_sizes, int n_in,
                              void* d_out, int out_size, void* d_ws, size_t ws_size,
                              hipStream_t stream)
{
    (void)in_sizes; (void)n_in; (void)out_size; (void)ws_size;
    // fp32 device inputs and fp32 output (reference dtypes); bf16 internal compute
    const float* x  = (const float*)d_in[0];
    // d_in[1] = mask: causal, implemented directly
    const float* qw = (const float*)d_in[2];
    const float* qb = (const float*)d_in[3];
    const float* kw = (const float*)d_in[4];
    const float* kb = (const float*)d_in[5];
    const float* vw = (const float*)d_in[6];
    const float* vb = (const float*)d_in[7];
    const float* ow = (const float*)d_in[8];
    const float* obias = (const float*)d_in[9];

    uint8_t* ws = (uint8_t*)d_ws;
    u16* Xb  = (u16*)(ws);                 // 16 MiB [Mtok][Dd]
    u16* Wqb = (u16*)(ws + 16 * MiB);      //  8 MiB [Dd][Dd] (row = out feature)
    u16* Wkb = (u16*)(ws + 24 * MiB);
    u16* Wvb = (u16*)(ws + 32 * MiB);
    u16* Wob = (u16*)(ws + 40 * MiB);
    u16* Qb  = (u16*)(ws + 48 * MiB);      // 16 MiB [BH][S][DH]
    u16* Kb  = (u16*)(ws + 64 * MiB);      // 16 MiB
    u16* Vb  = (u16*)(ws + 80 * MiB);      // 16 MiB
    u16* Vt  = Xb;                         // Xb dead after QKV gemms; [BH][DH][S]
    u16* Ob  = Vb;                         // Vb dead after transpose; attn out

    const int nX = Mtok * Dd;              // 8,388,608
    const int nW = Dd * Dd;                // 4,194,304
    dim3 blk(256);
    cvt_bf16<<<nX / 2048, blk, 0, stream>>>(x,  Xb,  nX);
    cvt_bf16<<<nW / 2048, blk, 0, stream>>>(qw, Wqb, nW);
    cvt_bf16<<<nW / 2048, blk, 0, stream>>>(kw, Wkb, nW);
    cvt_bf16<<<nW / 2048, blk, 0, stream>>>(vw, Wvb, nW);
    cvt_bf16<<<nW / 2048, blk, 0, stream>>>(ow, Wob, nW);

    gemm_qkv<<<dim3(Mtok / 128, Dd / 128, 3), blk, 0, stream>>>(
        Xb, Wqb, Wkb, Wvb, qb, kb, vb, Qb, Kb, Vb);
    transpose_v<<<dim3(Ss / 64, 64), blk, 0, stream>>>(Vb, Vt);
    attn<<<dim3(Ss / 128, 64), dim3(512), 0, stream>>>(Qb, Kb, Vt, Ob);
    gemm_oproj<<<dim3(Mtok / 128, Dd / 128, 1), blk, 0, stream>>>(
        Ob, Wob, obias, (float*)d_out);
}

// Round 6
// 342.399 us; speedup vs baseline: 1.9776x; 1.2091x over previous
//
#include <hip/hip_runtime.h>
#include <stdint.h>

#define Hh   32
#define Ss   2048
#define Dd   2048
#define DHd  64
#define Mtok 4096   // B*S
#define MiB  (1u << 20)

typedef unsigned short u16;
typedef u16   u16x4  __attribute__((ext_vector_type(4)));
typedef u16   u16x8  __attribute__((ext_vector_type(8)));
typedef short bf16x8 __attribute__((ext_vector_type(8)));
typedef float f32x4  __attribute__((ext_vector_type(4)));

__device__ __forceinline__ u16 f2bf(float f) {
    union { float f; uint32_t u; } v; v.f = f;
    uint32_t r = v.u + 0x7fffu + ((v.u >> 16) & 1u);   // RNE
    return (u16)(r >> 16);
}
__device__ __forceinline__ uint32_t cvtpk_bf16(float lo, float hi) {
    uint32_t r;
    asm volatile("v_cvt_pk_bf16_f32 %0, %1, %2" : "=v"(r) : "v"(lo), "v"(hi));
    return r;
}
__device__ __forceinline__ void gld_lds16(const void* g, void* l) {
    __builtin_amdgcn_global_load_lds(
        (const __attribute__((address_space(1))) uint32_t*)g,
        (__attribute__((address_space(3))) uint32_t*)l,
        16, 0, 0);
}

// ---------------- fp32 -> bf16 convert ----------------
__global__ void cvt_bf16(const float* __restrict__ src, u16* __restrict__ dst, int n)
{
    const int i = (blockIdx.x * 256 + threadIdx.x) * 8;
    if (i + 8 > n) return;
    f32x4 a = *(const f32x4*)(src + i);
    f32x4 b = *(const f32x4*)(src + i + 4);
    u16x8 o;
    o[0] = f2bf(a[0]); o[1] = f2bf(a[1]); o[2] = f2bf(a[2]); o[3] = f2bf(a[3]);
    o[4] = f2bf(b[0]); o[5] = f2bf(b[1]); o[6] = f2bf(b[2]); o[7] = f2bf(b[3]);
    *(u16x8*)(dst + i) = o;
}

// ---------------- GEMM core: C[128x128] += A[128xK] * W[128xK]^T (both K-major bf16) ----------------
__device__ __forceinline__ void gemm_core(const u16* __restrict__ Ap, const u16* __restrict__ Wp,
                                          u16* As, u16* Bs, f32x4 acc[4][4])
{
    const int tid = threadIdx.x, wid = tid >> 6, lane = tid & 63;
    const int l15 = lane & 15, lg = lane >> 4;
    const int wr = wid >> 1, wc = wid & 1;

    for (int kt = 0; kt < Dd; kt += 64) {
#pragma unroll
        for (int c = 0; c < 4; ++c) {
            const int chunk = c * 4 + wid;          // wave-uniform
            const int eoff  = chunk * 512;          // elem offset of 1KB LDS chunk
            const int le    = eoff + lane * 8;      // this lane's element
            const int row = le >> 6, col = le & 63; // [128][64] tile
            gld_lds16(Ap + (size_t)row * Dd + kt + col, As + eoff);
            gld_lds16(Wp + (size_t)row * Dd + kt + col, Bs + eoff);
        }
        __syncthreads();
#pragma unroll
        for (int ks = 0; ks < 2; ++ks) {
            bf16x8 af[4], bw[4];
#pragma unroll
            for (int i = 0; i < 4; ++i)
                af[i] = *(const bf16x8*)(As + (wr * 64 + i * 16 + l15) * 64 + ks * 32 + lg * 8);
#pragma unroll
            for (int i = 0; i < 4; ++i)
                bw[i] = *(const bf16x8*)(Bs + (wc * 64 + i * 16 + l15) * 64 + ks * 32 + lg * 8);
#pragma unroll
            for (int mi = 0; mi < 4; ++mi)
#pragma unroll
                for (int ni = 0; ni < 4; ++ni)
                    acc[mi][ni] = __builtin_amdgcn_mfma_f32_16x16x32_bf16(af[mi], bw[ni], acc[mi][ni], 0, 0, 0);
        }
        __syncthreads();
    }
}

// ---------------- fused QKV projection ----------------
__global__ __launch_bounds__(256) void gemm_qkv(
    const u16* __restrict__ X,
    const u16* __restrict__ Wq, const u16* __restrict__ Wk, const u16* __restrict__ Wv,
    const float* __restrict__ Bq, const float* __restrict__ Bk, const float* __restrict__ Bv,
    u16* __restrict__ Qo, u16* __restrict__ Ko, u16* __restrict__ Vo)
{
    __shared__ __align__(16) u16 As[128 * 64];
    __shared__ __align__(16) u16 Bs[128 * 64];
    const int z = blockIdx.z;
    const u16*   W   = (z == 0) ? Wq : ((z == 1) ? Wk : Wv);
    const float* Bi  = (z == 0) ? Bq : ((z == 1) ? Bk : Bv);
    u16*         Out = (z == 0) ? Qo : ((z == 1) ? Ko : Vo);
    const float scale = (z == 0) ? 0.125f : 1.0f;   // DH^-0.5 on Q (post-bias, like reference)

    const int m0 = blockIdx.x * 128, n0 = blockIdx.y * 128;
    f32x4 acc[4][4] = {};
    gemm_core(X + (size_t)m0 * Dd, W + (size_t)n0 * Dd, As, Bs, acc);

    const int tid = threadIdx.x, wid = tid >> 6, lane = tid & 63;
    const int l15 = lane & 15, lg = lane >> 4;
    const int wr = wid >> 1, wc = wid & 1;
#pragma unroll
    for (int ni = 0; ni < 4; ++ni) {
        const int n = n0 + wc * 64 + ni * 16 + l15;
        const float bv = Bi[n];
        const int h = n >> 6, dh = n & 63;
#pragma unroll
        for (int mi = 0; mi < 4; ++mi) {
#pragma unroll
            for (int r = 0; r < 4; ++r) {
                const int m = m0 + wr * 64 + mi * 16 + lg * 4 + r;
                const int b = m >> 11, s = m & 2047;
                Out[(((size_t)b * Hh + h) * Ss + s) * DHd + dh] = f2bf((acc[mi][ni][r] + bv) * scale);
            }
        }
    }
}

// ---------------- output projection (fp32 out, per harness contract) ----------------
__global__ __launch_bounds__(256) void gemm_oproj(
    const u16* __restrict__ A, const u16* __restrict__ W,
    const float* __restrict__ Bi, float* __restrict__ Out)
{
    __shared__ __align__(16) u16 As[128 * 64];
    __shared__ __align__(16) u16 Bs[128 * 64];
    const int m0 = blockIdx.x * 128, n0 = blockIdx.y * 128;
    f32x4 acc[4][4] = {};
    gemm_core(A + (size_t)m0 * Dd, W + (size_t)n0 * Dd, As, Bs, acc);

    const int tid = threadIdx.x, wid = tid >> 6, lane = tid & 63;
    const int l15 = lane & 15, lg = lane >> 4;
    const int wr = wid >> 1, wc = wid & 1;
#pragma unroll
    for (int ni = 0; ni < 4; ++ni) {
        const int n = n0 + wc * 64 + ni * 16 + l15;
        const float bv = Bi[n];
#pragma unroll
        for (int mi = 0; mi < 4; ++mi) {
#pragma unroll
            for (int r = 0; r < 4; ++r) {
                const int m = m0 + wr * 64 + mi * 16 + lg * 4 + r;
                Out[(size_t)m * Dd + n] = acc[mi][ni][r] + bv;
            }
        }
    }
}

// ---------------- V transpose: [BH][S][DH] -> [BH][DH][S] ----------------
__global__ void transpose_v(const u16* __restrict__ Vsrc, u16* __restrict__ Vdst)
{
    __shared__ __align__(16) u16 t[64 * 68];   // pad stride 68 elems
    const int bh = blockIdx.y, s0 = blockIdx.x * 64;
    const int tid = threadIdx.x;
    {
        const int r = tid >> 2, cq = (tid & 3) * 16;
        const u16* src = Vsrc + ((size_t)bh * Ss + s0 + r) * DHd;
#pragma unroll
        for (int j = 0; j < 4; ++j) {
            u16x4 v = *(const u16x4*)(src + cq + j * 4);
            *(u16x4*)&t[r * 68 + cq + j * 4] = v;
        }
    }
    __syncthreads();
    {
        const int d = tid >> 2, sq = (tid & 3) * 16;
        u16* dst = Vdst + ((size_t)bh * DHd + d) * Ss + s0;
#pragma unroll
        for (int j = 0; j < 4; ++j) {
            u16x4 v;
            v.x = t[(sq + j * 4 + 0) * 68 + d];
            v.y = t[(sq + j * 4 + 1) * 68 + d];
            v.z = t[(sq + j * 4 + 2) * 68 + d];
            v.w = t[(sq + j * 4 + 3) * 68 + d];
            *(u16x4*)(dst + sq + j * 4) = v;
        }
    }
}

// ---------------- flash attention (causal), swapped-operand softmax ----------------
// 8 waves/block (512 thr), QBLK=16/wave, KVBLK=64 double-buffered XOR-swizzled LDS.
// QK^T computed as mfma(K,Q): lane l15 = q, holds 16 kv-scores in regs ->
// in-lane softmax + 2 shfl_xor. PV computed as mfma(V^T,P): output stays in
// q=l15 orientation (rescale/normalize are in-lane scalars).
__device__ __forceinline__ void stage_kv(const u16* __restrict__ Kg, const u16* __restrict__ Vg,
                                         u16* Kl, u16* Vl, int kv0, int tid)
{
    // 512 threads x 16B = one full 64x64 bf16 tile per instruction
    const int u    = tid;                         // 16B-chunk id 0..511
    const int row  = u >> 3;                      // 64 rows, 8 chunks each
    const int csrc = ((u & 7) ^ (row & 7)) * 8;   // pre-swizzled source col (elems)
    const int base = (u & ~63) * 8;               // wave-uniform LDS elem base
    gld_lds16(Kg + (size_t)(kv0 + row) * DHd + csrc, Kl + base);
    gld_lds16(Vg + (size_t)row * Ss + kv0 + csrc, Vl + base);
}

__global__ __launch_bounds__(512) void attn(
    const u16* __restrict__ Qb, const u16* __restrict__ Kb,
    const u16* __restrict__ Vt, u16* __restrict__ Ob)
{
    __shared__ __align__(16) u16 Kl[2][4096];
    __shared__ __align__(16) u16 Vl[2][4096];
    __shared__ __align__(16) u16 Pl[8][1024];   // per wave: 16 q x 64 kv (swizzled)
    const int bh = blockIdx.y;
    const int b = bh >> 5, h = bh & 31;
    const int tid = threadIdx.x;
    const int wid = tid >> 6, lane = tid & 63;
    const int l15 = lane & 15, lg = lane >> 4;
    const int q0 = blockIdx.x * 128 + wid * 16;
    const int qrow = q0 + l15;
    char* PwB = (char*)Pl[wid];
    const int psw = (l15 & 7) << 4;            // this lane's P-row swizzle

    const u16* Qp = Qb + ((size_t)bh * Ss + q0) * DHd;
    const u16* Kp = Kb + (size_t)bh * Ss * DHd;
    const u16* Vp = Vt + (size_t)bh * DHd * Ss;

    // Q as B-fragment: col = l15 = q, k = lg*8+e
    bf16x8 bq[2];
#pragma unroll
    for (int kf = 0; kf < 2; ++kf)
        bq[kf] = *(const bf16x8*)(Qp + (size_t)l15 * DHd + kf * 32 + lg * 8);

    f32x4 o[4] = {};            // o[nb][r]: q = qrow, d = nb*16 + lg*4 + r
    float m_r = -3e38f, l_r = 0.f;

    const int nt = 2 * (blockIdx.x + 1);

    stage_kv(Kp, Vp, Kl[0], Vl[0], 0, tid);
    __syncthreads();

    for (int t = 0; t < nt; ++t) {
        if (t + 1 < nt)
            stage_kv(Kp, Vp, Kl[(t + 1) & 1], Vl[(t + 1) & 1], (t + 1) * 64, tid);
        const u16* Kc = Kl[t & 1];
        const u16* Vc = Vl[t & 1];
        const int kv0 = t * 64;

        if (kv0 <= q0 + 15) {   // wave has unmasked work in this tile
            // QK^T swapped: s[nb]: q = qrow, kv = kv0 + nb*16 + lg*4 + r
            f32x4 s[4] = {};
#pragma unroll
            for (int nb = 0; nb < 4; ++nb) {
                const int krow = nb * 16 + l15;
                const char* rb = (const char*)(Kc + krow * 64);
                const int sw = (krow & 7) << 4;
#pragma unroll
                for (int kf = 0; kf < 2; ++kf) {
                    bf16x8 ak = *(const bf16x8*)(rb + ((kf * 64 + lg * 16) ^ sw));
                    s[nb] = __builtin_amdgcn_mfma_f32_16x16x32_bf16(ak, bq[kf], s[nb], 0, 0, 0);
                }
            }
            if (kv0 + 63 > q0) {   // diagonal region: mask kv > q
#pragma unroll
                for (int nb = 0; nb < 4; ++nb)
#pragma unroll
                    for (int r = 0; r < 4; ++r)
                        if (kv0 + nb * 16 + lg * 4 + r > qrow) s[nb][r] = -3e38f;
            }
            // in-lane row max over 16 + 2 shfl (lanes sharing q differ in lg)
            float pm = -3e38f;
#pragma unroll
            for (int nb = 0; nb < 4; ++nb)
#pragma unroll
                for (int r = 0; r < 4; ++r) pm = fmaxf(pm, s[nb][r]);
            pm = fmaxf(pm, __shfl_xor(pm, 16, 64));
            pm = fmaxf(pm, __shfl_xor(pm, 32, 64));
            const float mn = fmaxf(m_r, pm);
            const float al = __expf(m_r - mn);
            m_r = mn;
            float rs = 0.f;
            float p[4][4];
#pragma unroll
            for (int nb = 0; nb < 4; ++nb)
#pragma unroll
                for (int r = 0; r < 4; ++r) {
                    p[nb][r] = __expf(s[nb][r] - mn);
                    rs += p[nb][r];
                }
            rs += __shfl_xor(rs, 16, 64);
            rs += __shfl_xor(rs, 32, 64);
            l_r = l_r * al + rs;
#pragma unroll
            for (int nb = 0; nb < 4; ++nb)
#pragma unroll
                for (int r = 0; r < 4; ++r) o[nb][r] *= al;

            // P -> LDS as bf16 pairs (swizzled row l15), then read as B-fragment
            char* prow = PwB + l15 * 128;
#pragma unroll
            for (int nb = 0; nb < 4; ++nb) {
                const uint32_t w0 = cvtpk_bf16(p[nb][0], p[nb][1]);
                const uint32_t w1 = cvtpk_bf16(p[nb][2], p[nb][3]);
                const int c0 = (nb * 32 + lg * 8) ^ psw;   // byte col of kv pair base
                *(uint32_t*)(prow + c0)     = w0;
                *(uint32_t*)(prow + c0 + 4) = w1;
            }
            bf16x8 pa[2];
#pragma unroll
            for (int ks = 0; ks < 2; ++ks)
                pa[ks] = *(const bf16x8*)(prow + ((ks * 64 + lg * 16) ^ psw));

            // PV swapped: o[nb] += V^T . P  (A = V^T rows d, B = P cols q)
#pragma unroll
            for (int nb = 0; nb < 4; ++nb) {
                const int vrow = nb * 16 + l15;
                const char* rb = (const char*)(Vc + vrow * 64);
                const int sw = (vrow & 7) << 4;
#pragma unroll
                for (int ks = 0; ks < 2; ++ks) {
                    bf16x8 bv = *(const bf16x8*)(rb + ((ks * 64 + lg * 16) ^ sw));
                    o[nb] = __builtin_amdgcn_mfma_f32_16x16x32_bf16(bv, pa[ks], o[nb], 0, 0, 0);
                }
            }
        }
        __syncthreads();
    }

    const float inv = 1.0f / l_r;
    u16* orow = Ob + ((size_t)b * Ss + qrow) * Dd + h * DHd;
#pragma unroll
    for (int nb = 0; nb < 4; ++nb) {
        u16x4 pk;
#pragma unroll
        for (int r = 0; r < 4; ++r) pk[r] = f2bf(o[nb][r] * inv);
        *(u16x4*)(orow + nb * 16 + lg * 4) = pk;
    }
}

extern "C" void kernel_launch(void* const* d_in, const int* in_sizes, int n_in,
                              void* d_out, int out_size, void* d_ws, size_t ws_size,
                              hipStream_t stream)
{
    (void)in_sizes; (void)n_in; (void)out_size; (void)ws_size;
    // fp32 device inputs and fp32 output (reference dtypes); bf16 internal compute
    const float* x  = (const float*)d_in[0];
    // d_in[1] = mask: causal, implemented directly
    const float* qw = (const float*)d_in[2];
    const float* qb = (const float*)d_in[3];
    const float* kw = (const float*)d_in[4];
    const float* kb = (const float*)d_in[5];
    const float* vw = (const float*)d_in[6];
    const float* vb = (const float*)d_in[7];
    const float* ow = (const float*)d_in[8];
    const float* obias = (const float*)d_in[9];

    uint8_t* ws = (uint8_t*)d_ws;
    u16* Xb  = (u16*)(ws);                 // 16 MiB [Mtok][Dd]
    u16* Wqb = (u16*)(ws + 16 * MiB);      //  8 MiB [Dd][Dd] (row = out feature)
    u16* Wkb = (u16*)(ws + 24 * MiB);
    u16* Wvb = (u16*)(ws + 32 * MiB);
    u16* Wob = (u16*)(ws + 40 * MiB);
    u16* Qb  = (u16*)(ws + 48 * MiB);      // 16 MiB [BH][S][DH]
    u16* Kb  = (u16*)(ws + 64 * MiB);      // 16 MiB
    u16* Vb  = (u16*)(ws + 80 * MiB);      // 16 MiB
    u16* Vt  = Xb;                         // Xb dead after QKV gemms; [BH][DH][S]
    u16* Ob  = Vb;                         // Vb dead after transpose; attn out

    const int nX = Mtok * Dd;              // 8,388,608
    const int nW = Dd * Dd;                // 4,194,304
    dim3 blk(256);
    cvt_bf16<<<nX / 2048, blk, 0, stream>>>(x,  Xb,  nX);
    cvt_bf16<<<nW / 2048, blk, 0, stream>>>(qw, Wqb, nW);
    cvt_bf16<<<nW / 2048, blk, 0, stream>>>(kw, Wkb, nW);
    cvt_bf16<<<nW / 2048, blk, 0, stream>>>(vw, Wvb, nW);
    cvt_bf16<<<nW / 2048, blk, 0, stream>>>(ow, Wob, nW);

    gemm_qkv<<<dim3(Mtok / 128, Dd / 128, 3), blk, 0, stream>>>(
        Xb, Wqb, Wkb, Wvb, qb, kb, vb, Qb, Kb, Vb);
    transpose_v<<<dim3(Ss / 64, 64), blk, 0, stream>>>(Vb, Vt);
    attn<<<dim3(Ss / 128, 64), dim3(512), 0, stream>>>(Qb, Kb, Vt, Ob);
    gemm_oproj<<<dim3(Mtok / 128, Dd / 128, 1), blk, 0, stream>>>(
        Ob, Wob, obias, (float*)d_out);
}

// Round 7
// 291.917 us; speedup vs baseline: 2.3196x; 1.1729x over previous
//
#include <hip/hip_runtime.h>
#include <stdint.h>

#define Hh   32
#define Ss   2048
#define Dd   2048
#define DHd  64
#define Mtok 4096   // B*S
#define MiB  (1u << 20)
#define NTK  32     // K tiles of 64 in Dd

typedef unsigned short u16;
typedef u16   u16x4  __attribute__((ext_vector_type(4)));
typedef u16   u16x8  __attribute__((ext_vector_type(8)));
typedef short bf16x8 __attribute__((ext_vector_type(8)));
typedef float f32x4  __attribute__((ext_vector_type(4)));

__device__ __forceinline__ u16 f2bf(float f) {
    union { float f; uint32_t u; } v; v.f = f;
    uint32_t r = v.u + 0x7fffu + ((v.u >> 16) & 1u);   // RNE
    return (u16)(r >> 16);
}
__device__ __forceinline__ uint32_t cvtpk_bf16(float lo, float hi) {
    uint32_t r;
    asm volatile("v_cvt_pk_bf16_f32 %0, %1, %2" : "=v"(r) : "v"(lo), "v"(hi));
    return r;
}
__device__ __forceinline__ void gld_lds16(const void* g, void* l) {
    __builtin_amdgcn_global_load_lds(
        (const __attribute__((address_space(1))) uint32_t*)g,
        (__attribute__((address_space(3))) uint32_t*)l,
        16, 0, 0);
}

// ---------------- fp32 -> bf16 convert ----------------
__global__ void cvt_bf16(const float* __restrict__ src, u16* __restrict__ dst, int n)
{
    const int i = (blockIdx.x * 256 + threadIdx.x) * 8;
    if (i + 8 > n) return;
    f32x4 a = *(const f32x4*)(src + i);
    f32x4 b = *(const f32x4*)(src + i + 4);
    u16x8 o;
    o[0] = f2bf(a[0]); o[1] = f2bf(a[1]); o[2] = f2bf(a[2]); o[3] = f2bf(a[3]);
    o[4] = f2bf(b[0]); o[5] = f2bf(b[1]); o[6] = f2bf(b[2]); o[7] = f2bf(b[3]);
    *(u16x8*)(dst + i) = o;
}

// ================= 8-phase GEMM core (BM=128, BN=256, BK=64, 8 waves) =================
// C[128x256] = A[128xK] * W[256xK]^T, K-major bf16 both. LDS 96KB: 2 buf x {A 2x4096, B 2x8192}.
// Swizzle: unit rows of 32 elems (64B); 16B chunk c4 = ((row&1)<<2)|(col>>3), phys = c4 ^ ((row>>1)&7).

__device__ __forceinline__ void stage_unitA(const u16* __restrict__ src, u16* dst, int wid, int lane)
{   // 128 rows x 32 cols, 1 load/thread
    const int P = wid * 64 + lane;
    const int rp = P >> 3, c4p = P & 7, c4 = c4p ^ (rp & 7);
    const int r = rp * 2 + (c4 >> 2), c = (c4 & 3) * 8;
    gld_lds16(src + (size_t)r * Dd + c, dst + wid * 512);
}
__device__ __forceinline__ void stage_unitB(const u16* __restrict__ src, u16* dst, int wid, int lane)
{   // 256 rows x 32 cols, 2 loads/thread
#pragma unroll
    for (int j = 0; j < 2; ++j) {
        const int P = j * 512 + wid * 64 + lane;
        const int rp = P >> 3, c4p = P & 7, c4 = c4p ^ (rp & 7);
        const int r = rp * 2 + (c4 >> 2), c = (c4 & 3) * 8;
        gld_lds16(src + (size_t)r * Dd + c, dst + j * 4096 + wid * 512);
    }
}
__device__ __forceinline__ bf16x8 frag_read(const u16* unit, int r, int lg)
{
    const int rp = r >> 1;
    const int c4 = ((r & 1) << 2) | lg;
    const int c4p = c4 ^ (rp & 7);
    return *(const bf16x8*)(unit + rp * 64 + c4p * 8);
}
#define SB() __builtin_amdgcn_sched_barrier(0)

__device__ __forceinline__ void gemm8_core(const u16* __restrict__ Ab, const u16* __restrict__ Wb,
                                           u16* L, f32x4 acc[4][4],
                                           int wid, int lane, int l15, int lg, int wm, int wn)
{
    u16* const L0 = L;
    u16* const L1 = L + 24576;
    // prologue: tile0 fully + tile1 {Bk0,Ak0,Bk1}; leaves 5 loads in flight
    stage_unitB(Wb + 0,  L0 + 8192,  wid, lane);
    stage_unitA(Ab + 0,  L0 + 0,     wid, lane);
    stage_unitB(Wb + 32, L0 + 16384, wid, lane);
    stage_unitA(Ab + 32, L0 + 4096,  wid, lane);
    stage_unitB(Wb + 64, L1 + 8192,  wid, lane);
    stage_unitA(Ab + 64, L1 + 0,     wid, lane);
    stage_unitB(Wb + 96, L1 + 16384, wid, lane);
    asm volatile("s_waitcnt vmcnt(5)" ::: "memory");
    SB(); __builtin_amdgcn_s_barrier(); SB();

    bf16x8 bfr[4];
    const int aro = wm * 64 + l15;
    const int bro = wn * 64 + l15;
#pragma unroll 2
    for (int t = 0; t < NTK; ++t) {
        u16* const Lc = (t & 1) ? L1 : L0;
        u16* const Ln = (t & 1) ? L0 : L1;
#pragma unroll
        for (int ph = 0; ph < 4; ++ph) {
            const int ks = ph >> 1, hf = ph & 1;
            const u16* Au = Lc + ks * 4096;
            const u16* Bu = Lc + 8192 + ks * 8192;
            if (hf == 0) {
#pragma unroll
                for (int ni = 0; ni < 4; ++ni)
                    bfr[ni] = frag_read(Bu, bro + ni * 16, lg);
            }
            bf16x8 a0 = frag_read(Au, aro + (hf * 2 + 0) * 16, lg);
            bf16x8 a1 = frag_read(Au, aro + (hf * 2 + 1) * 16, lg);
            // stage schedule: p1 completes tile t+1; p2-p4 stage tile t+2 into regions consumed a phase earlier
            if      (ph == 0) { if (t + 1 < NTK) stage_unitA(Ab + (t + 1) * 64 + 32, Ln + 4096,  wid, lane); }
            else if (ph == 1) { if (t + 2 < NTK) stage_unitB(Wb + (t + 2) * 64 + 0,  Lc + 8192,  wid, lane); }
            else if (ph == 2) { if (t + 2 < NTK) stage_unitA(Ab + (t + 2) * 64 + 0,  Lc + 0,     wid, lane); }
            else              { if (t + 2 < NTK) stage_unitB(Wb + (t + 2) * 64 + 32, Lc + 16384, wid, lane); }
            SB(); __builtin_amdgcn_s_barrier(); SB();
            asm volatile("s_waitcnt lgkmcnt(0)" ::: "memory");
            SB();
            __builtin_amdgcn_s_setprio(1);
#pragma unroll
            for (int ni = 0; ni < 4; ++ni) {
                acc[hf * 2 + 0][ni] = __builtin_amdgcn_mfma_f32_16x16x32_bf16(a0, bfr[ni], acc[hf * 2 + 0][ni], 0, 0, 0);
                acc[hf * 2 + 1][ni] = __builtin_amdgcn_mfma_f32_16x16x32_bf16(a1, bfr[ni], acc[hf * 2 + 1][ni], 0, 0, 0);
            }
            __builtin_amdgcn_s_setprio(0);
            if (ph == 3 && t < NTK - 1) {
                if (t + 2 < NTK) { asm volatile("s_waitcnt vmcnt(5)" ::: "memory"); }
                else             { asm volatile("s_waitcnt vmcnt(0)" ::: "memory"); }
            }
            SB(); __builtin_amdgcn_s_barrier(); SB();
        }
    }
}

// ---------------- fused QKV projection (8-phase core) ----------------
__global__ __launch_bounds__(512) void gemm_qkv8(
    const u16* __restrict__ X, const u16* __restrict__ Wcat,
    const float* __restrict__ Bq, const float* __restrict__ Bk, const float* __restrict__ Bv,
    u16* __restrict__ Qo, u16* __restrict__ Ko, u16* __restrict__ Vo)
{
    __shared__ __align__(16) u16 L[2 * 24576];   // 96 KB
    const int tid = threadIdx.x, wid = tid >> 6, lane = tid & 63;
    const int l15 = lane & 15, lg = lane >> 4;
    const int wm = wid >> 2, wn = wid & 3;
    const int m0 = blockIdx.x * 128, n0 = blockIdx.y * 256;

    f32x4 acc[4][4] = {};
    gemm8_core(X + (size_t)m0 * Dd, Wcat + (size_t)n0 * Dd, L, acc, wid, lane, l15, lg, wm, wn);

#pragma unroll
    for (int ni = 0; ni < 4; ++ni) {
        const int n = n0 + wn * 64 + ni * 16 + l15;
        const int z = n >> 11, nn = n & 2047;
        const float bv = (z == 0 ? Bq : z == 1 ? Bk : Bv)[nn];
        const float sc = (z == 0) ? 0.125f : 1.0f;
        u16* Out = (z == 0 ? Qo : z == 1 ? Ko : Vo);
        const int h = nn >> 6, dh = nn & 63;
#pragma unroll
        for (int mi = 0; mi < 4; ++mi)
#pragma unroll
            for (int r = 0; r < 4; ++r) {
                const int m = m0 + wm * 64 + mi * 16 + lg * 4 + r;
                const int b = m >> 11, s = m & 2047;
                Out[(((size_t)b * Hh + h) * Ss + s) * DHd + dh] = f2bf((acc[mi][ni][r] + bv) * sc);
            }
    }
}

// ---------------- output projection (8-phase core, fp32 out) ----------------
__global__ __launch_bounds__(512) void gemm_oproj8(
    const u16* __restrict__ A, const u16* __restrict__ W,
    const float* __restrict__ Bi, float* __restrict__ Out)
{
    __shared__ __align__(16) u16 L[2 * 24576];   // 96 KB
    const int tid = threadIdx.x, wid = tid >> 6, lane = tid & 63;
    const int l15 = lane & 15, lg = lane >> 4;
    const int wm = wid >> 2, wn = wid & 3;
    const int m0 = blockIdx.x * 128, n0 = blockIdx.y * 256;

    f32x4 acc[4][4] = {};
    gemm8_core(A + (size_t)m0 * Dd, W + (size_t)n0 * Dd, L, acc, wid, lane, l15, lg, wm, wn);

#pragma unroll
    for (int ni = 0; ni < 4; ++ni) {
        const int n = n0 + wn * 64 + ni * 16 + l15;
        const float bv = Bi[n];
#pragma unroll
        for (int mi = 0; mi < 4; ++mi)
#pragma unroll
            for (int r = 0; r < 4; ++r) {
                const int m = m0 + wm * 64 + mi * 16 + lg * 4 + r;
                Out[(size_t)m * Dd + n] = acc[mi][ni][r] + bv;
            }
    }
}

// ---------------- V transpose: [BH][S][DH] -> [BH][DH][S] ----------------
__global__ void transpose_v(const u16* __restrict__ Vsrc, u16* __restrict__ Vdst)
{
    __shared__ __align__(16) u16 t[64 * 68];   // pad stride 68 elems
    const int bh = blockIdx.y, s0 = blockIdx.x * 64;
    const int tid = threadIdx.x;
    {
        const int r = tid >> 2, cq = (tid & 3) * 16;
        const u16* src = Vsrc + ((size_t)bh * Ss + s0 + r) * DHd;
#pragma unroll
        for (int j = 0; j < 4; ++j) {
            u16x4 v = *(const u16x4*)(src + cq + j * 4);
            *(u16x4*)&t[r * 68 + cq + j * 4] = v;
        }
    }
    __syncthreads();
    {
        const int d = tid >> 2, sq = (tid & 3) * 16;
        u16* dst = Vdst + ((size_t)bh * DHd + d) * Ss + s0;
#pragma unroll
        for (int j = 0; j < 4; ++j) {
            u16x4 v;
            v.x = t[(sq + j * 4 + 0) * 68 + d];
            v.y = t[(sq + j * 4 + 1) * 68 + d];
            v.z = t[(sq + j * 4 + 2) * 68 + d];
            v.w = t[(sq + j * 4 + 3) * 68 + d];
            *(u16x4*)(dst + sq + j * 4) = v;
        }
    }
}

// ---------------- flash attention (causal), swapped-operand softmax ----------------
__device__ __forceinline__ void stage_kv(const u16* __restrict__ Kg, const u16* __restrict__ Vg,
                                         u16* Kl, u16* Vl, int kv0, int tid)
{
    const int u    = tid;                         // 16B-chunk id 0..511
    const int row  = u >> 3;                      // 64 rows, 8 chunks each
    const int csrc = ((u & 7) ^ (row & 7)) * 8;   // pre-swizzled source col (elems)
    const int base = (u & ~63) * 8;               // wave-uniform LDS elem base
    gld_lds16(Kg + (size_t)(kv0 + row) * DHd + csrc, Kl + base);
    gld_lds16(Vg + (size_t)row * Ss + kv0 + csrc, Vl + base);
}

__global__ __launch_bounds__(512) void attn(
    const u16* __restrict__ Qb, const u16* __restrict__ Kb,
    const u16* __restrict__ Vt, u16* __restrict__ Ob)
{
    __shared__ __align__(16) u16 Kl[2][4096];
    __shared__ __align__(16) u16 Vl[2][4096];
    __shared__ __align__(16) u16 Pl[8][1024];   // per wave: 16 q x 64 kv (swizzled)
    const int bh = blockIdx.y;
    const int b = bh >> 5, h = bh & 31;
    const int tid = threadIdx.x;
    const int wid = tid >> 6, lane = tid & 63;
    const int l15 = lane & 15, lg = lane >> 4;
    const int q0 = blockIdx.x * 128 + wid * 16;
    const int qrow = q0 + l15;
    char* PwB = (char*)Pl[wid];
    const int psw = (l15 & 7) << 4;            // this lane's P-row swizzle

    const u16* Qp = Qb + ((size_t)bh * Ss + q0) * DHd;
    const u16* Kp = Kb + (size_t)bh * Ss * DHd;
    const u16* Vp = Vt + (size_t)bh * DHd * Ss;

    bf16x8 bq[2];
#pragma unroll
    for (int kf = 0; kf < 2; ++kf)
        bq[kf] = *(const bf16x8*)(Qp + (size_t)l15 * DHd + kf * 32 + lg * 8);

    f32x4 o[4] = {};            // o[nb][r]: q = qrow, d = nb*16 + lg*4 + r
    float m_r = -3e38f, l_r = 0.f;

    const int nt = 2 * (blockIdx.x + 1);

    stage_kv(Kp, Vp, Kl[0], Vl[0], 0, tid);
    __syncthreads();

    for (int t = 0; t < nt; ++t) {
        if (t + 1 < nt)
            stage_kv(Kp, Vp, Kl[(t + 1) & 1], Vl[(t + 1) & 1], (t + 1) * 64, tid);
        const u16* Kc = Kl[t & 1];
        const u16* Vc = Vl[t & 1];
        const int kv0 = t * 64;

        if (kv0 <= q0 + 15) {
            f32x4 s[4] = {};
#pragma unroll
            for (int nb = 0; nb < 4; ++nb) {
                const int krow = nb * 16 + l15;
                const char* rb = (const char*)(Kc + krow * 64);
                const int sw = (krow & 7) << 4;
#pragma unroll
                for (int kf = 0; kf < 2; ++kf) {
                    bf16x8 ak = *(const bf16x8*)(rb + ((kf * 64 + lg * 16) ^ sw));
                    s[nb] = __builtin_amdgcn_mfma_f32_16x16x32_bf16(ak, bq[kf], s[nb], 0, 0, 0);
                }
            }
            if (kv0 + 63 > q0) {
#pragma unroll
                for (int nb = 0; nb < 4; ++nb)
#pragma unroll
                    for (int r = 0; r < 4; ++r)
                        if (kv0 + nb * 16 + lg * 4 + r > qrow) s[nb][r] = -3e38f;
            }
            float pm = -3e38f;
#pragma unroll
            for (int nb = 0; nb < 4; ++nb)
#pragma unroll
                for (int r = 0; r < 4; ++r) pm = fmaxf(pm, s[nb][r]);
            pm = fmaxf(pm, __shfl_xor(pm, 16, 64));
            pm = fmaxf(pm, __shfl_xor(pm, 32, 64));
            const float mn = fmaxf(m_r, pm);
            const float al = __expf(m_r - mn);
            m_r = mn;
            float rs = 0.f;
            float p[4][4];
#pragma unroll
            for (int nb = 0; nb < 4; ++nb)
#pragma unroll
                for (int r = 0; r < 4; ++r) {
                    p[nb][r] = __expf(s[nb][r] - mn);
                    rs += p[nb][r];
                }
            rs += __shfl_xor(rs, 16, 64);
            rs += __shfl_xor(rs, 32, 64);
            l_r = l_r * al + rs;
#pragma unroll
            for (int nb = 0; nb < 4; ++nb)
#pragma unroll
                for (int r = 0; r < 4; ++r) o[nb][r] *= al;

            char* prow = PwB + l15 * 128;
#pragma unroll
            for (int nb = 0; nb < 4; ++nb) {
                const uint32_t w0 = cvtpk_bf16(p[nb][0], p[nb][1]);
                const uint32_t w1 = cvtpk_bf16(p[nb][2], p[nb][3]);
                const int c0 = (nb * 32 + lg * 8) ^ psw;
                *(uint32_t*)(prow + c0)     = w0;
                *(uint32_t*)(prow + c0 + 4) = w1;
            }
            bf16x8 pa[2];
#pragma unroll
            for (int ks = 0; ks < 2; ++ks)
                pa[ks] = *(const bf16x8*)(prow + ((ks * 64 + lg * 16) ^ psw));

#pragma unroll
            for (int nb = 0; nb < 4; ++nb) {
                const int vrow = nb * 16 + l15;
                const char* rb = (const char*)(Vc + vrow * 64);
                const int sw = (vrow & 7) << 4;
#pragma unroll
                for (int ks = 0; ks < 2; ++ks) {
                    bf16x8 bv = *(const bf16x8*)(rb + ((ks * 64 + lg * 16) ^ sw));
                    o[nb] = __builtin_amdgcn_mfma_f32_16x16x32_bf16(bv, pa[ks], o[nb], 0, 0, 0);
                }
            }
        }
        __syncthreads();
    }

    const float inv = 1.0f / l_r;
    u16* orow = Ob + ((size_t)b * Ss + qrow) * Dd + h * DHd;
#pragma unroll
    for (int nb = 0; nb < 4; ++nb) {
        u16x4 pk;
#pragma unroll
        for (int r = 0; r < 4; ++r) pk[r] = f2bf(o[nb][r] * inv);
        *(u16x4*)(orow + nb * 16 + lg * 4) = pk;
    }
}

extern "C" void kernel_launch(void* const* d_in, const int* in_sizes, int n_in,
                              void* d_out, int out_size, void* d_ws, size_t ws_size,
                              hipStream_t stream)
{
    (void)in_sizes; (void)n_in; (void)out_size; (void)ws_size;
    const float* x  = (const float*)d_in[0];
    // d_in[1] = mask: causal, implemented directly
    const float* qw = (const float*)d_in[2];
    const float* qb = (const float*)d_in[3];
    const float* kw = (const float*)d_in[4];
    const float* kb = (const float*)d_in[5];
    const float* vw = (const float*)d_in[6];
    const float* vb = (const float*)d_in[7];
    const float* ow = (const float*)d_in[8];
    const float* obias = (const float*)d_in[9];

    uint8_t* ws = (uint8_t*)d_ws;
    u16* Xb  = (u16*)(ws);                 // 16 MiB [Mtok][Dd]
    u16* Wcat= (u16*)(ws + 16 * MiB);      // 24 MiB: Wq|Wk|Wv rows (6144 x 2048)
    u16* Wob = (u16*)(ws + 40 * MiB);      //  8 MiB
    u16* Qb  = (u16*)(ws + 48 * MiB);      // 16 MiB [BH][S][DH]
    u16* Kb  = (u16*)(ws + 64 * MiB);      // 16 MiB
    u16* Vb  = (u16*)(ws + 80 * MiB);      // 16 MiB
    u16* Vt  = Xb;                         // Xb dead after QKV gemms; [BH][DH][S]
    u16* Ob  = Vb;                         // Vb dead after transpose; attn out

    const int nX = Mtok * Dd;              // 8,388,608
    const int nW = Dd * Dd;                // 4,194,304
    dim3 blk(256);
    cvt_bf16<<<nX / 2048, blk, 0, stream>>>(x,  Xb,  nX);
    cvt_bf16<<<nW / 2048, blk, 0, stream>>>(qw, Wcat,          nW);
    cvt_bf16<<<nW / 2048, blk, 0, stream>>>(kw, Wcat + nW,     nW);
    cvt_bf16<<<nW / 2048, blk, 0, stream>>>(vw, Wcat + 2 * nW, nW);
    cvt_bf16<<<nW / 2048, blk, 0, stream>>>(ow, Wob, nW);

    gemm_qkv8<<<dim3(Mtok / 128, 6144 / 256), dim3(512), 0, stream>>>(
        Xb, Wcat, qb, kb, vb, Qb, Kb, Vb);
    transpose_v<<<dim3(Ss / 64, 64), blk, 0, stream>>>(Vb, Vt);
    attn<<<dim3(Ss / 128, 64), dim3(512), 0, stream>>>(Qb, Kb, Vt, Ob);
    gemm_oproj8<<<dim3(Mtok / 128, Dd / 256), dim3(512), 0, stream>>>(
        Ob, Wob, obias, (float*)d_out);
}

// Round 8
// 248.271 us; speedup vs baseline: 2.7274x; 1.1758x over previous
//
#include <hip/hip_runtime.h>
#include <stdint.h>

#define Hh   32
#define Ss   2048
#define Dd   2048
#define DHd  64
#define Mtok 4096   // B*S
#define MiB  (1u << 20)
#define NTK  32     // K tiles of 64 in Dd

typedef unsigned short u16;
typedef u16   u16x4  __attribute__((ext_vector_type(4)));
typedef u16   u16x8  __attribute__((ext_vector_type(8)));
typedef short bf16x8 __attribute__((ext_vector_type(8)));
typedef float f32x4  __attribute__((ext_vector_type(4)));

__device__ __forceinline__ u16 f2bf(float f) {
    union { float f; uint32_t u; } v; v.f = f;
    uint32_t r = v.u + 0x7fffu + ((v.u >> 16) & 1u);   // RNE
    return (u16)(r >> 16);
}
__device__ __forceinline__ uint32_t cvtpk_bf16(float lo, float hi) {
    uint32_t r;
    asm volatile("v_cvt_pk_bf16_f32 %0, %1, %2" : "=v"(r) : "v"(lo), "v"(hi));
    return r;
}
__device__ __forceinline__ void gld_lds16(const void* g, void* l) {
    __builtin_amdgcn_global_load_lds(
        (const __attribute__((address_space(1))) uint32_t*)g,
        (__attribute__((address_space(3))) uint32_t*)l,
        16, 0, 0);
}
#define SB() __builtin_amdgcn_sched_barrier(0)

// ---------------- fp32 -> bf16 convert ----------------
__global__ void cvt_bf16(const float* __restrict__ src, u16* __restrict__ dst, int n)
{
    const int i = (blockIdx.x * 256 + threadIdx.x) * 8;
    if (i + 8 > n) return;
    f32x4 a = *(const f32x4*)(src + i);
    f32x4 b = *(const f32x4*)(src + i + 4);
    u16x8 o;
    o[0] = f2bf(a[0]); o[1] = f2bf(a[1]); o[2] = f2bf(a[2]); o[3] = f2bf(a[3]);
    o[4] = f2bf(b[0]); o[5] = f2bf(b[1]); o[6] = f2bf(b[2]); o[7] = f2bf(b[3]);
    *(u16x8*)(dst + i) = o;
}

// ================= 8-phase GEMM core (BM=128, BN=256, BK=64, 8 waves) =================
// C[128x256] = A[128xK] * W[256xK]^T, K-major bf16 both. LDS 96KB: 2 buf x {A 2x4096, B 2x8192}.
// Swizzle: unit rows of 32 elems (64B); 16B chunk c4 = ((row&1)<<2)|(col>>3), phys = c4 ^ ((row>>1)&7).

__device__ __forceinline__ void stage_unitA(const u16* __restrict__ src, u16* dst, int wid, int lane)
{   // 128 rows x 32 cols, 1 load/thread
    const int P = wid * 64 + lane;
    const int rp = P >> 3, c4p = P & 7, c4 = c4p ^ (rp & 7);
    const int r = rp * 2 + (c4 >> 2), c = (c4 & 3) * 8;
    gld_lds16(src + (size_t)r * Dd + c, dst + wid * 512);
}
__device__ __forceinline__ void stage_unitB(const u16* __restrict__ src, u16* dst, int wid, int lane)
{   // 256 rows x 32 cols, 2 loads/thread
#pragma unroll
    for (int j = 0; j < 2; ++j) {
        const int P = j * 512 + wid * 64 + lane;
        const int rp = P >> 3, c4p = P & 7, c4 = c4p ^ (rp & 7);
        const int r = rp * 2 + (c4 >> 2), c = (c4 & 3) * 8;
        gld_lds16(src + (size_t)r * Dd + c, dst + j * 4096 + wid * 512);
    }
}
__device__ __forceinline__ bf16x8 frag_read(const u16* unit, int r, int lg)
{
    const int rp = r >> 1;
    const int c4 = ((r & 1) << 2) | lg;
    const int c4p = c4 ^ (rp & 7);
    return *(const bf16x8*)(unit + rp * 64 + c4p * 8);
}

__device__ __forceinline__ void gemm8_core(const u16* __restrict__ Ab, const u16* __restrict__ Wb,
                                           u16* L, f32x4 acc[4][4],
                                           int wid, int lane, int l15, int lg, int wm, int wn)
{
    u16* const L0 = L;
    u16* const L1 = L + 24576;
    // prologue: tile0 fully + tile1 {Bk0,Ak0,Bk1}; leaves 5 loads in flight
    stage_unitB(Wb + 0,  L0 + 8192,  wid, lane);
    stage_unitA(Ab + 0,  L0 + 0,     wid, lane);
    stage_unitB(Wb + 32, L0 + 16384, wid, lane);
    stage_unitA(Ab + 32, L0 + 4096,  wid, lane);
    stage_unitB(Wb + 64, L1 + 8192,  wid, lane);
    stage_unitA(Ab + 64, L1 + 0,     wid, lane);
    stage_unitB(Wb + 96, L1 + 16384, wid, lane);
    asm volatile("s_waitcnt vmcnt(5)" ::: "memory");
    SB(); __builtin_amdgcn_s_barrier(); SB();

    bf16x8 bfr[4];
    const int aro = wm * 64 + l15;
    const int bro = wn * 64 + l15;
#pragma unroll 2
    for (int t = 0; t < NTK; ++t) {
        u16* const Lc = (t & 1) ? L1 : L0;
        u16* const Ln = (t & 1) ? L0 : L1;
#pragma unroll
        for (int ph = 0; ph < 4; ++ph) {
            const int ks = ph >> 1, hf = ph & 1;
            const u16* Au = Lc + ks * 4096;
            const u16* Bu = Lc + 8192 + ks * 8192;
            if (hf == 0) {
#pragma unroll
                for (int ni = 0; ni < 4; ++ni)
                    bfr[ni] = frag_read(Bu, bro + ni * 16, lg);
            }
            bf16x8 a0 = frag_read(Au, aro + (hf * 2 + 0) * 16, lg);
            bf16x8 a1 = frag_read(Au, aro + (hf * 2 + 1) * 16, lg);
            // stage schedule: p1 completes tile t+1; p2-p4 stage tile t+2 into regions consumed a phase earlier
            if      (ph == 0) { if (t + 1 < NTK) stage_unitA(Ab + (t + 1) * 64 + 32, Ln + 4096,  wid, lane); }
            else if (ph == 1) { if (t + 2 < NTK) stage_unitB(Wb + (t + 2) * 64 + 0,  Lc + 8192,  wid, lane); }
            else if (ph == 2) { if (t + 2 < NTK) stage_unitA(Ab + (t + 2) * 64 + 0,  Lc + 0,     wid, lane); }
            else              { if (t + 2 < NTK) stage_unitB(Wb + (t + 2) * 64 + 32, Lc + 16384, wid, lane); }
            SB(); __builtin_amdgcn_s_barrier(); SB();
            asm volatile("s_waitcnt lgkmcnt(0)" ::: "memory");
            SB();
            __builtin_amdgcn_s_setprio(1);
#pragma unroll
            for (int ni = 0; ni < 4; ++ni) {
                acc[hf * 2 + 0][ni] = __builtin_amdgcn_mfma_f32_16x16x32_bf16(a0, bfr[ni], acc[hf * 2 + 0][ni], 0, 0, 0);
                acc[hf * 2 + 1][ni] = __builtin_amdgcn_mfma_f32_16x16x32_bf16(a1, bfr[ni], acc[hf * 2 + 1][ni], 0, 0, 0);
            }
            __builtin_amdgcn_s_setprio(0);
            if (ph == 3 && t < NTK - 1) {
                if (t + 2 < NTK) { asm volatile("s_waitcnt vmcnt(5)" ::: "memory"); }
                else             { asm volatile("s_waitcnt vmcnt(0)" ::: "memory"); }
            }
            SB(); __builtin_amdgcn_s_barrier(); SB();
        }
    }
}

// ---------------- fused QKV projection (8-phase core) ----------------
__global__ __launch_bounds__(512) void gemm_qkv8(
    const u16* __restrict__ X, const u16* __restrict__ Wcat,
    const float* __restrict__ Bq, const float* __restrict__ Bk, const float* __restrict__ Bv,
    u16* __restrict__ Qo, u16* __restrict__ Ko, u16* __restrict__ Vo)
{
    __shared__ __align__(16) u16 L[2 * 24576];   // 96 KB
    const int tid = threadIdx.x, wid = tid >> 6, lane = tid & 63;
    const int l15 = lane & 15, lg = lane >> 4;
    const int wm = wid >> 2, wn = wid & 3;
    const int m0 = blockIdx.x * 128, n0 = blockIdx.y * 256;

    f32x4 acc[4][4] = {};
    gemm8_core(X + (size_t)m0 * Dd, Wcat + (size_t)n0 * Dd, L, acc, wid, lane, l15, lg, wm, wn);

#pragma unroll
    for (int ni = 0; ni < 4; ++ni) {
        const int n = n0 + wn * 64 + ni * 16 + l15;
        const int z = n >> 11, nn = n & 2047;
        const float bv = (z == 0 ? Bq : z == 1 ? Bk : Bv)[nn];
        const float sc = (z == 0) ? 0.125f : 1.0f;
        u16* Out = (z == 0 ? Qo : z == 1 ? Ko : Vo);
        const int h = nn >> 6, dh = nn & 63;
#pragma unroll
        for (int mi = 0; mi < 4; ++mi)
#pragma unroll
            for (int r = 0; r < 4; ++r) {
                const int m = m0 + wm * 64 + mi * 16 + lg * 4 + r;
                const int b = m >> 11, s = m & 2047;
                Out[(((size_t)b * Hh + h) * Ss + s) * DHd + dh] = f2bf((acc[mi][ni][r] + bv) * sc);
            }
    }
}

// ---------------- output projection (8-phase core, fp32 out) ----------------
__global__ __launch_bounds__(512) void gemm_oproj8(
    const u16* __restrict__ A, const u16* __restrict__ W,
    const float* __restrict__ Bi, float* __restrict__ Out)
{
    __shared__ __align__(16) u16 L[2 * 24576];   // 96 KB
    const int tid = threadIdx.x, wid = tid >> 6, lane = tid & 63;
    const int l15 = lane & 15, lg = lane >> 4;
    const int wm = wid >> 2, wn = wid & 3;
    const int m0 = blockIdx.x * 128, n0 = blockIdx.y * 256;

    f32x4 acc[4][4] = {};
    gemm8_core(A + (size_t)m0 * Dd, W + (size_t)n0 * Dd, L, acc, wid, lane, l15, lg, wm, wn);

#pragma unroll
    for (int ni = 0; ni < 4; ++ni) {
        const int n = n0 + wn * 64 + ni * 16 + l15;
        const float bv = Bi[n];
#pragma unroll
        for (int mi = 0; mi < 4; ++mi)
#pragma unroll
            for (int r = 0; r < 4; ++r) {
                const int m = m0 + wm * 64 + mi * 16 + lg * 4 + r;
                Out[(size_t)m * Dd + n] = acc[mi][ni][r] + bv;
            }
    }
}

// ---------------- V transpose: [BH][S][DH] -> [BH][DH][S] ----------------
__global__ void transpose_v(const u16* __restrict__ Vsrc, u16* __restrict__ Vdst)
{
    __shared__ __align__(16) u16 t[64 * 68];   // pad stride 68 elems
    const int bh = blockIdx.y, s0 = blockIdx.x * 64;
    const int tid = threadIdx.x;
    {
        const int r = tid >> 2, cq = (tid & 3) * 16;
        const u16* src = Vsrc + ((size_t)bh * Ss + s0 + r) * DHd;
#pragma unroll
        for (int j = 0; j < 4; ++j) {
            u16x4 v = *(const u16x4*)(src + cq + j * 4);
            *(u16x4*)&t[r * 68 + cq + j * 4] = v;
        }
    }
    __syncthreads();
    {
        const int d = tid >> 2, sq = (tid & 3) * 16;
        u16* dst = Vdst + ((size_t)bh * DHd + d) * Ss + s0;
#pragma unroll
        for (int j = 0; j < 4; ++j) {
            u16x4 v;
            v.x = t[(sq + j * 4 + 0) * 68 + d];
            v.y = t[(sq + j * 4 + 1) * 68 + d];
            v.z = t[(sq + j * 4 + 2) * 68 + d];
            v.w = t[(sq + j * 4 + 3) * 68 + d];
            *(u16x4*)(dst + sq + j * 4) = v;
        }
    }
}

// ---------------- flash attention (causal), paired q-tiles + counted vmcnt ----------------
// Block bx handles q-tiles bx and 15-bx (uniform 34 kv-units). 8 waves, 16 q-rows each
// per tile. KVBLK=64 double-buffered XOR-swizzled LDS; raw barriers, vmcnt(2) counted wait.
__device__ __forceinline__ void stage_kv(const u16* __restrict__ Kg, const u16* __restrict__ Vg,
                                         u16* Kl, u16* Vl, int kv0, int tid)
{
    const int u    = tid;                         // 16B-chunk id 0..511
    const int row  = u >> 3;                      // 64 rows, 8 chunks each
    const int csrc = ((u & 7) ^ (row & 7)) * 8;   // pre-swizzled source col (elems)
    const int base = (u & ~63) * 8;               // wave-uniform LDS elem base
    gld_lds16(Kg + (size_t)(kv0 + row) * DHd + csrc, Kl + base);
    gld_lds16(Vg + (size_t)row * Ss + kv0 + csrc, Vl + base);
}

__device__ __forceinline__ void attn_tile(
    const u16* __restrict__ Kc, const u16* __restrict__ Vc, int kv0,
    int q0, int qrow, int l15, int lg, int psw,
    const bf16x8* __restrict__ bq, f32x4* __restrict__ o,
    float& m_r, float& l_r, char* __restrict__ prow)
{
    if (kv0 > q0 + 15) return;
    f32x4 s[4] = {};
    __builtin_amdgcn_s_setprio(1);
#pragma unroll
    for (int nb = 0; nb < 4; ++nb) {
        const int krow = nb * 16 + l15;
        const char* rb = (const char*)(Kc + krow * 64);
        const int sw = (krow & 7) << 4;
#pragma unroll
        for (int kf = 0; kf < 2; ++kf) {
            bf16x8 ak = *(const bf16x8*)(rb + ((kf * 64 + lg * 16) ^ sw));
            s[nb] = __builtin_amdgcn_mfma_f32_16x16x32_bf16(ak, bq[kf], s[nb], 0, 0, 0);
        }
    }
    __builtin_amdgcn_s_setprio(0);
    if (kv0 + 63 > q0) {   // diagonal region: mask kv > q
#pragma unroll
        for (int nb = 0; nb < 4; ++nb)
#pragma unroll
            for (int r = 0; r < 4; ++r)
                if (kv0 + nb * 16 + lg * 4 + r > qrow) s[nb][r] = -3e38f;
    }
    float pm = -3e38f;
#pragma unroll
    for (int nb = 0; nb < 4; ++nb)
#pragma unroll
        for (int r = 0; r < 4; ++r) pm = fmaxf(pm, s[nb][r]);
    pm = fmaxf(pm, __shfl_xor(pm, 16, 64));
    pm = fmaxf(pm, __shfl_xor(pm, 32, 64));
    // defer-max (T13): skip o-rescale while max growth <= 8
    const bool full = !__all(pm - m_r <= 8.0f);
    float mn = m_r, al = 1.0f;
    if (full) {
        mn = fmaxf(m_r, pm);
        al = __expf(m_r - mn);
#pragma unroll
        for (int nb = 0; nb < 4; ++nb)
#pragma unroll
            for (int r = 0; r < 4; ++r) o[nb][r] *= al;
    }
    float rs = 0.f;
    float p[4][4];
#pragma unroll
    for (int nb = 0; nb < 4; ++nb)
#pragma unroll
        for (int r = 0; r < 4; ++r) { p[nb][r] = __expf(s[nb][r] - mn); rs += p[nb][r]; }
    rs += __shfl_xor(rs, 16, 64);
    rs += __shfl_xor(rs, 32, 64);
    l_r = l_r * al + rs;
    m_r = mn;
#pragma unroll
    for (int nb = 0; nb < 4; ++nb) {
        const uint32_t w0 = cvtpk_bf16(p[nb][0], p[nb][1]);
        const uint32_t w1 = cvtpk_bf16(p[nb][2], p[nb][3]);
        const int c0 = (nb * 32 + lg * 8) ^ psw;
        *(uint32_t*)(prow + c0)     = w0;
        *(uint32_t*)(prow + c0 + 4) = w1;
    }
    bf16x8 pa[2];
#pragma unroll
    for (int ks = 0; ks < 2; ++ks)
        pa[ks] = *(const bf16x8*)(prow + ((ks * 64 + lg * 16) ^ psw));
    __builtin_amdgcn_s_setprio(1);
#pragma unroll
    for (int nb = 0; nb < 4; ++nb) {
        const int vrow = nb * 16 + l15;
        const char* rb = (const char*)(Vc + vrow * 64);
        const int sw = (vrow & 7) << 4;
#pragma unroll
        for (int ks = 0; ks < 2; ++ks) {
            bf16x8 bv = *(const bf16x8*)(rb + ((ks * 64 + lg * 16) ^ sw));
            o[nb] = __builtin_amdgcn_mfma_f32_16x16x32_bf16(bv, pa[ks], o[nb], 0, 0, 0);
        }
    }
    __builtin_amdgcn_s_setprio(0);
}

__global__ __launch_bounds__(512) void attn(
    const u16* __restrict__ Qb, const u16* __restrict__ Kb,
    const u16* __restrict__ Vt, u16* __restrict__ Ob)
{
    __shared__ __align__(16) u16 Kl[2][4096];
    __shared__ __align__(16) u16 Vl[2][4096];
    __shared__ __align__(16) u16 PlA[8][1024];
    __shared__ __align__(16) u16 PlB[8][1024];
    const int bh = blockIdx.y;
    const int b = bh >> 5, h = bh & 31;
    const int tid = threadIdx.x;
    const int wid = tid >> 6, lane = tid & 63;
    const int l15 = lane & 15, lg = lane >> 4;
    const int bxA = blockIdx.x, bxB = 15 - bxA;          // paired q-tiles
    const int q0A = bxA * 128 + wid * 16, q0B = bxB * 128 + wid * 16;
    const int qrowA = q0A + l15, qrowB = q0B + l15;
    char* prowA = (char*)PlA[wid] + l15 * 128;
    char* prowB = (char*)PlB[wid] + l15 * 128;
    const int psw = (l15 & 7) << 4;

    const u16* Kp = Kb + (size_t)bh * Ss * DHd;
    const u16* Vp = Vt + (size_t)bh * DHd * Ss;

    bf16x8 bqA[2], bqB[2];
    {
        const u16* QpA = Qb + ((size_t)bh * Ss + q0A) * DHd;
        const u16* QpB = Qb + ((size_t)bh * Ss + q0B) * DHd;
#pragma unroll
        for (int kf = 0; kf < 2; ++kf) {
            bqA[kf] = *(const bf16x8*)(QpA + (size_t)l15 * DHd + kf * 32 + lg * 8);
            bqB[kf] = *(const bf16x8*)(QpB + (size_t)l15 * DHd + kf * 32 + lg * 8);
        }
    }
    asm volatile("s_waitcnt vmcnt(0)" ::: "memory");   // drain Q loads: in-loop vmem = gld_lds only

    f32x4 oA[4] = {}, oB[4] = {};
    float mA = -3e38f, lA = 0.f, mB = -3e38f, lB = 0.f;
    const int nt = 2 * (bxB + 1);

    stage_kv(Kp, Vp, Kl[0], Vl[0], 0, tid);
    for (int t = 0; t < nt; ++t) {
        if (t + 1 < nt) {
            stage_kv(Kp, Vp, Kl[(t + 1) & 1], Vl[(t + 1) & 1], (t + 1) * 64, tid);
            asm volatile("s_waitcnt vmcnt(2)" ::: "memory");   // stage(t) landed (counted, no drain)
        } else {
            asm volatile("s_waitcnt vmcnt(0)" ::: "memory");
        }
        SB(); __builtin_amdgcn_s_barrier(); SB();
        const int kv0 = t * 64;
        attn_tile(Kl[t & 1], Vl[t & 1], kv0, q0A, qrowA, l15, lg, psw, bqA, oA, mA, lA, prowA);
        attn_tile(Kl[t & 1], Vl[t & 1], kv0, q0B, qrowB, l15, lg, psw, bqB, oB, mB, lB, prowB);
        SB(); __builtin_amdgcn_s_barrier(); SB();
    }

    {
        const float inv = 1.0f / lA;
        u16* orow = Ob + ((size_t)b * Ss + qrowA) * Dd + h * DHd;
#pragma unroll
        for (int nb = 0; nb < 4; ++nb) {
            u16x4 pk;
#pragma unroll
            for (int r = 0; r < 4; ++r) pk[r] = f2bf(oA[nb][r] * inv);
            *(u16x4*)(orow + nb * 16 + lg * 4) = pk;
        }
    }
    {
        const float inv = 1.0f / lB;
        u16* orow = Ob + ((size_t)b * Ss + qrowB) * Dd + h * DHd;
#pragma unroll
        for (int nb = 0; nb < 4; ++nb) {
            u16x4 pk;
#pragma unroll
            for (int r = 0; r < 4; ++r) pk[r] = f2bf(oB[nb][r] * inv);
            *(u16x4*)(orow + nb * 16 + lg * 4) = pk;
        }
    }
}

extern "C" void kernel_launch(void* const* d_in, const int* in_sizes, int n_in,
                              void* d_out, int out_size, void* d_ws, size_t ws_size,
                              hipStream_t stream)
{
    (void)in_sizes; (void)n_in; (void)out_size; (void)ws_size;
    const float* x  = (const float*)d_in[0];
    // d_in[1] = mask: causal, implemented directly
    const float* qw = (const float*)d_in[2];
    const float* qb = (const float*)d_in[3];
    const float* kw = (const float*)d_in[4];
    const float* kb = (const float*)d_in[5];
    const float* vw = (const float*)d_in[6];
    const float* vb = (const float*)d_in[7];
    const float* ow = (const float*)d_in[8];
    const float* obias = (const float*)d_in[9];

    uint8_t* ws = (uint8_t*)d_ws;
    u16* Xb  = (u16*)(ws);                 // 16 MiB [Mtok][Dd]
    u16* Wcat= (u16*)(ws + 16 * MiB);      // 24 MiB: Wq|Wk|Wv rows (6144 x 2048)
    u16* Wob = (u16*)(ws + 40 * MiB);      //  8 MiB
    u16* Qb  = (u16*)(ws + 48 * MiB);      // 16 MiB [BH][S][DH]
    u16* Kb  = (u16*)(ws + 64 * MiB);      // 16 MiB
    u16* Vb  = (u16*)(ws + 80 * MiB);      // 16 MiB
    u16* Vt  = Xb;                         // Xb dead after QKV gemms; [BH][DH][S]
    u16* Ob  = Vb;                         // Vb dead after transpose; attn out

    const int nX = Mtok * Dd;              // 8,388,608
    const int nW = Dd * Dd;                // 4,194,304
    dim3 blk(256);
    cvt_bf16<<<nX / 2048, blk, 0, stream>>>(x,  Xb,  nX);
    cvt_bf16<<<nW / 2048, blk, 0, stream>>>(qw, Wcat,          nW);
    cvt_bf16<<<nW / 2048, blk, 0, stream>>>(kw, Wcat + nW,     nW);
    cvt_bf16<<<nW / 2048, blk, 0, stream>>>(vw, Wcat + 2 * nW, nW);
    cvt_bf16<<<nW / 2048, blk, 0, stream>>>(ow, Wob, nW);

    gemm_qkv8<<<dim3(Mtok / 128, 6144 / 256), dim3(512), 0, stream>>>(
        Xb, Wcat, qb, kb, vb, Qb, Kb, Vb);
    transpose_v<<<dim3(Ss / 64, 64), blk, 0, stream>>>(Vb, Vt);
    attn<<<dim3(8, 64), dim3(512), 0, stream>>>(Qb, Kb, Vt, Ob);
    gemm_oproj8<<<dim3(Mtok / 128, Dd / 256), dim3(512), 0, stream>>>(
        Ob, Wob, obias, (float*)d_out);
}

// Round 9
// 239.196 us; speedup vs baseline: 2.8309x; 1.0379x over previous
//
#include <hip/hip_runtime.h>
#include <stdint.h>

#define Hh   32
#define Ss   2048
#define Dd   2048
#define DHd  64
#define Mtok 4096   // B*S
#define MiB  (1u << 20)
#define NTK  32     // K tiles of 64 in Dd

typedef unsigned short u16;
typedef u16   u16x4  __attribute__((ext_vector_type(4)));
typedef u16   u16x8  __attribute__((ext_vector_type(8)));
typedef short bf16x8 __attribute__((ext_vector_type(8)));
typedef float f32x4  __attribute__((ext_vector_type(4)));

__device__ __forceinline__ u16 f2bf(float f) {
    union { float f; uint32_t u; } v; v.f = f;
    uint32_t r = v.u + 0x7fffu + ((v.u >> 16) & 1u);   // RNE
    return (u16)(r >> 16);
}
__device__ __forceinline__ uint32_t cvtpk_bf16(float lo, float hi) {
    uint32_t r;
    asm volatile("v_cvt_pk_bf16_f32 %0, %1, %2" : "=v"(r) : "v"(lo), "v"(hi));
    return r;
}
__device__ __forceinline__ void gld_lds16(const void* g, void* l) {
    __builtin_amdgcn_global_load_lds(
        (const __attribute__((address_space(1))) uint32_t*)g,
        (__attribute__((address_space(3))) uint32_t*)l,
        16, 0, 0);
}
#define SB() __builtin_amdgcn_sched_barrier(0)

// ---------------- fused fp32 -> bf16 convert (X + 4 weights, one launch) ----------------
__global__ void cvt_all(const float* __restrict__ x,  const float* __restrict__ qw,
                        const float* __restrict__ kw, const float* __restrict__ vw,
                        const float* __restrict__ ow,
                        u16* __restrict__ Xb, u16* __restrict__ Wcat, u16* __restrict__ Wob)
{
    const size_t nX = 1u << 23, nW = 1u << 22;
    size_t i = ((size_t)blockIdx.x * 256 + threadIdx.x) * 8;
    const float* src; u16* dst; size_t off;
    if (i < nX) { src = x; dst = Xb; off = i; }
    else {
        size_t j = i - nX;
        int seg = (int)(j >> 22);
        off = j & (nW - 1);
        src = (seg == 0) ? qw : (seg == 1) ? kw : (seg == 2) ? vw : ow;
        dst = (seg == 3) ? Wob : Wcat + (size_t)seg * nW;
    }
    f32x4 a = *(const f32x4*)(src + off);
    f32x4 b = *(const f32x4*)(src + off + 4);
    u16x8 o;
    o[0] = f2bf(a[0]); o[1] = f2bf(a[1]); o[2] = f2bf(a[2]); o[3] = f2bf(a[3]);
    o[4] = f2bf(b[0]); o[5] = f2bf(b[1]); o[6] = f2bf(b[2]); o[7] = f2bf(b[3]);
    *(u16x8*)(dst + off) = o;
}

// ================= 2-phase GEMM core (BM=128, BN=256, BK=64, 8 waves) =================
// C[128x256] = A[128xK] * W[256xK]^T, K-major bf16 both. LDS 96KB: 2 buf x {A 2x4096, B 2x8192}.
// Swizzle: unit rows of 32 elems (64B); 16B chunk c4 = ((row&1)<<2)|(col>>3), phys = c4 ^ ((row>>1)&7).
// Per phase: 8 ds_read_b128 + 1 stage-pair (3 loads) + 16 MFMA + counted vmcnt(6) + ONE barrier.

__device__ __forceinline__ void stage_unitA(const u16* __restrict__ src, u16* dst, int wid, int lane)
{   // 128 rows x 32 cols, 1 load/thread
    const int P = wid * 64 + lane;
    const int rp = P >> 3, c4p = P & 7, c4 = c4p ^ (rp & 7);
    const int r = rp * 2 + (c4 >> 2), c = (c4 & 3) * 8;
    gld_lds16(src + (size_t)r * Dd + c, dst + wid * 512);
}
__device__ __forceinline__ void stage_unitB(const u16* __restrict__ src, u16* dst, int wid, int lane)
{   // 256 rows x 32 cols, 2 loads/thread
#pragma unroll
    for (int j = 0; j < 2; ++j) {
        const int P = j * 512 + wid * 64 + lane;
        const int rp = P >> 3, c4p = P & 7, c4 = c4p ^ (rp & 7);
        const int r = rp * 2 + (c4 >> 2), c = (c4 & 3) * 8;
        gld_lds16(src + (size_t)r * Dd + c, dst + j * 4096 + wid * 512);
    }
}
__device__ __forceinline__ bf16x8 frag_read(const u16* unit, int r, int lg)
{
    const int rp = r >> 1;
    const int c4 = ((r & 1) << 2) | lg;
    const int c4p = c4 ^ (rp & 7);
    return *(const bf16x8*)(unit + rp * 64 + c4p * 8);
}

__device__ __forceinline__ void gemm2_core(const u16* __restrict__ Ab, const u16* __restrict__ Wb,
                                           u16* L, f32x4 acc[4][4],
                                           int wid, int lane, int l15, int lg, int wm, int wn)
{
    u16* const L0 = L;
    u16* const L1 = L + 24576;
    // prologue: SP(0,ks0), SP(0,ks1), SP(1,ks0) = 9 loads; ensure SP(0,ks0) landed
    stage_unitA(Ab + 0,  L0 + 0,     wid, lane);
    stage_unitB(Wb + 0,  L0 + 8192,  wid, lane);
    stage_unitA(Ab + 32, L0 + 4096,  wid, lane);
    stage_unitB(Wb + 32, L0 + 16384, wid, lane);
    stage_unitA(Ab + 64, L1 + 0,     wid, lane);
    stage_unitB(Wb + 64, L1 + 8192,  wid, lane);
    asm volatile("s_waitcnt vmcnt(6)" ::: "memory");
    SB(); __builtin_amdgcn_s_barrier(); SB();

    const int aro = wm * 64 + l15;
    const int bro = wn * 64 + l15;
#pragma unroll 2
    for (int t = 0; t < NTK; ++t) {
        u16* const Lc = (t & 1) ? L1 : L0;
        u16* const Ln = (t & 1) ? L0 : L1;
#pragma unroll
        for (int ph = 0; ph < 2; ++ph) {
            const u16* Au = Lc + ph * 4096;
            const u16* Bu = Lc + 8192 + ph * 8192;
            bf16x8 bfr[4], a[4];
#pragma unroll
            for (int ni = 0; ni < 4; ++ni) bfr[ni] = frag_read(Bu, bro + ni * 16, lg);
#pragma unroll
            for (int mi = 0; mi < 4; ++mi) a[mi] = frag_read(Au, aro + mi * 16, lg);
            // stage schedule: ph0 -> SP(t+1,ks1) into Ln; ph1 -> SP(t+2,ks0) into Lc.ks0
            if (ph == 0) {
                if (t + 1 < NTK) {
                    stage_unitA(Ab + (t + 1) * 64 + 32, Ln + 4096,  wid, lane);
                    stage_unitB(Wb + (t + 1) * 64 + 32, Ln + 16384, wid, lane);
                }
            } else {
                if (t + 2 < NTK) {
                    stage_unitA(Ab + (t + 2) * 64, Lc + 0,    wid, lane);
                    stage_unitB(Wb + (t + 2) * 64, Lc + 8192, wid, lane);
                }
            }
            asm volatile("s_waitcnt lgkmcnt(0)" ::: "memory");
            SB();
            __builtin_amdgcn_s_setprio(1);
#pragma unroll
            for (int mi = 0; mi < 4; ++mi)
#pragma unroll
                for (int ni = 0; ni < 4; ++ni)
                    acc[mi][ni] = __builtin_amdgcn_mfma_f32_16x16x32_bf16(a[mi], bfr[ni], acc[mi][ni], 0, 0, 0);
            __builtin_amdgcn_s_setprio(0);
            // counted wait guarding next phase's frag reads
            const bool deep = (ph == 0) ? (t + 1 < NTK) : (t + 2 < NTK);
            if (deep) { asm volatile("s_waitcnt vmcnt(6)" ::: "memory"); }
            else      { asm volatile("s_waitcnt vmcnt(0)" ::: "memory"); }
            SB(); __builtin_amdgcn_s_barrier(); SB();
        }
    }
}

// ---------------- fused QKV projection (2-phase core) ----------------
__global__ __launch_bounds__(512) void gemm_qkv8(
    const u16* __restrict__ X, const u16* __restrict__ Wcat,
    const float* __restrict__ Bq, const float* __restrict__ Bk, const float* __restrict__ Bv,
    u16* __restrict__ Qo, u16* __restrict__ Ko, u16* __restrict__ Vo)
{
    __shared__ __align__(16) u16 L[2 * 24576];   // 96 KB
    const int tid = threadIdx.x, wid = tid >> 6, lane = tid & 63;
    const int l15 = lane & 15, lg = lane >> 4;
    const int wm = wid >> 2, wn = wid & 3;
    const int m0 = blockIdx.x * 128, n0 = blockIdx.y * 256;

    f32x4 acc[4][4] = {};
    gemm2_core(X + (size_t)m0 * Dd, Wcat + (size_t)n0 * Dd, L, acc, wid, lane, l15, lg, wm, wn);

#pragma unroll
    for (int ni = 0; ni < 4; ++ni) {
        const int n = n0 + wn * 64 + ni * 16 + l15;
        const int z = n >> 11, nn = n & 2047;
        const float bv = (z == 0 ? Bq : z == 1 ? Bk : Bv)[nn];
        const float sc = (z == 0) ? 0.125f : 1.0f;
        u16* Out = (z == 0 ? Qo : z == 1 ? Ko : Vo);
        const int h = nn >> 6, dh = nn & 63;
#pragma unroll
        for (int mi = 0; mi < 4; ++mi)
#pragma unroll
            for (int r = 0; r < 4; ++r) {
                const int m = m0 + wm * 64 + mi * 16 + lg * 4 + r;
                const int b = m >> 11, s = m & 2047;
                Out[(((size_t)b * Hh + h) * Ss + s) * DHd + dh] = f2bf((acc[mi][ni][r] + bv) * sc);
            }
    }
}

// ---------------- output projection (2-phase core, fp32 out) ----------------
__global__ __launch_bounds__(512) void gemm_oproj8(
    const u16* __restrict__ A, const u16* __restrict__ W,
    const float* __restrict__ Bi, float* __restrict__ Out)
{
    __shared__ __align__(16) u16 L[2 * 24576];   // 96 KB
    const int tid = threadIdx.x, wid = tid >> 6, lane = tid & 63;
    const int l15 = lane & 15, lg = lane >> 4;
    const int wm = wid >> 2, wn = wid & 3;
    const int m0 = blockIdx.x * 128, n0 = blockIdx.y * 256;

    f32x4 acc[4][4] = {};
    gemm2_core(A + (size_t)m0 * Dd, W + (size_t)n0 * Dd, L, acc, wid, lane, l15, lg, wm, wn);

#pragma unroll
    for (int ni = 0; ni < 4; ++ni) {
        const int n = n0 + wn * 64 + ni * 16 + l15;
        const float bv = Bi[n];
#pragma unroll
        for (int mi = 0; mi < 4; ++mi)
#pragma unroll
            for (int r = 0; r < 4; ++r) {
                const int m = m0 + wm * 64 + mi * 16 + lg * 4 + r;
                Out[(size_t)m * Dd + n] = acc[mi][ni][r] + bv;
            }
    }
}

// ---------------- V transpose: [BH][S][DH] -> [BH][DH][S] ----------------
__global__ void transpose_v(const u16* __restrict__ Vsrc, u16* __restrict__ Vdst)
{
    __shared__ __align__(16) u16 t[64 * 68];   // pad stride 68 elems
    const int bh = blockIdx.y, s0 = blockIdx.x * 64;
    const int tid = threadIdx.x;
    {
        const int r = tid >> 2, cq = (tid & 3) * 16;
        const u16* src = Vsrc + ((size_t)bh * Ss + s0 + r) * DHd;
#pragma unroll
        for (int j = 0; j < 4; ++j) {
            u16x4 v = *(const u16x4*)(src + cq + j * 4);
            *(u16x4*)&t[r * 68 + cq + j * 4] = v;
        }
    }
    __syncthreads();
    {
        const int d = tid >> 2, sq = (tid & 3) * 16;
        u16* dst = Vdst + ((size_t)bh * DHd + d) * Ss + s0;
#pragma unroll
        for (int j = 0; j < 4; ++j) {
            u16x4 v;
            v.x = t[(sq + j * 4 + 0) * 68 + d];
            v.y = t[(sq + j * 4 + 1) * 68 + d];
            v.z = t[(sq + j * 4 + 2) * 68 + d];
            v.w = t[(sq + j * 4 + 3) * 68 + d];
            *(u16x4*)(dst + sq + j * 4) = v;
        }
    }
}

// ---------------- flash attention (causal), paired q-tiles + counted vmcnt ----------------
__device__ __forceinline__ void stage_kv(const u16* __restrict__ Kg, const u16* __restrict__ Vg,
                                         u16* Kl, u16* Vl, int kv0, int tid)
{
    const int u    = tid;                         // 16B-chunk id 0..511
    const int row  = u >> 3;                      // 64 rows, 8 chunks each
    const int csrc = ((u & 7) ^ (row & 7)) * 8;   // pre-swizzled source col (elems)
    const int base = (u & ~63) * 8;               // wave-uniform LDS elem base
    gld_lds16(Kg + (size_t)(kv0 + row) * DHd + csrc, Kl + base);
    gld_lds16(Vg + (size_t)row * Ss + kv0 + csrc, Vl + base);
}

__device__ __forceinline__ void attn_tile(
    const u16* __restrict__ Kc, const u16* __restrict__ Vc, int kv0,
    int q0, int qrow, int l15, int lg, int psw,
    const bf16x8* __restrict__ bq, f32x4* __restrict__ o,
    float& m_r, float& l_r, char* __restrict__ prow)
{
    if (kv0 > q0 + 15) return;
    f32x4 s[4] = {};
    __builtin_amdgcn_s_setprio(1);
#pragma unroll
    for (int nb = 0; nb < 4; ++nb) {
        const int krow = nb * 16 + l15;
        const char* rb = (const char*)(Kc + krow * 64);
        const int sw = (krow & 7) << 4;
#pragma unroll
        for (int kf = 0; kf < 2; ++kf) {
            bf16x8 ak = *(const bf16x8*)(rb + ((kf * 64 + lg * 16) ^ sw));
            s[nb] = __builtin_amdgcn_mfma_f32_16x16x32_bf16(ak, bq[kf], s[nb], 0, 0, 0);
        }
    }
    __builtin_amdgcn_s_setprio(0);
    if (kv0 + 63 > q0) {   // diagonal region: mask kv > q
#pragma unroll
        for (int nb = 0; nb < 4; ++nb)
#pragma unroll
            for (int r = 0; r < 4; ++r)
                if (kv0 + nb * 16 + lg * 4 + r > qrow) s[nb][r] = -3e38f;
    }
    float pm = -3e38f;
#pragma unroll
    for (int nb = 0; nb < 4; ++nb)
#pragma unroll
        for (int r = 0; r < 4; ++r) pm = fmaxf(pm, s[nb][r]);
    pm = fmaxf(pm, __shfl_xor(pm, 16, 64));
    pm = fmaxf(pm, __shfl_xor(pm, 32, 64));
    // defer-max (T13): skip o-rescale while max growth <= 8
    const bool full = !__all(pm - m_r <= 8.0f);
    float mn = m_r, al = 1.0f;
    if (full) {
        mn = fmaxf(m_r, pm);
        al = __expf(m_r - mn);
#pragma unroll
        for (int nb = 0; nb < 4; ++nb)
#pragma unroll
            for (int r = 0; r < 4; ++r) o[nb][r] *= al;
    }
    float rs = 0.f;
    float p[4][4];
#pragma unroll
    for (int nb = 0; nb < 4; ++nb)
#pragma unroll
        for (int r = 0; r < 4; ++r) { p[nb][r] = __expf(s[nb][r] - mn); rs += p[nb][r]; }
    rs += __shfl_xor(rs, 16, 64);
    rs += __shfl_xor(rs, 32, 64);
    l_r = l_r * al + rs;
    m_r = mn;
#pragma unroll
    for (int nb = 0; nb < 4; ++nb) {
        const uint32_t w0 = cvtpk_bf16(p[nb][0], p[nb][1]);
        const uint32_t w1 = cvtpk_bf16(p[nb][2], p[nb][3]);
        const int c0 = (nb * 32 + lg * 8) ^ psw;
        *(uint32_t*)(prow + c0)     = w0;
        *(uint32_t*)(prow + c0 + 4) = w1;
    }
    bf16x8 pa[2];
#pragma unroll
    for (int ks = 0; ks < 2; ++ks)
        pa[ks] = *(const bf16x8*)(prow + ((ks * 64 + lg * 16) ^ psw));
    __builtin_amdgcn_s_setprio(1);
#pragma unroll
    for (int nb = 0; nb < 4; ++nb) {
        const int vrow = nb * 16 + l15;
        const char* rb = (const char*)(Vc + vrow * 64);
        const int sw = (vrow & 7) << 4;
#pragma unroll
        for (int ks = 0; ks < 2; ++ks) {
            bf16x8 bv = *(const bf16x8*)(rb + ((ks * 64 + lg * 16) ^ sw));
            o[nb] = __builtin_amdgcn_mfma_f32_16x16x32_bf16(bv, pa[ks], o[nb], 0, 0, 0);
        }
    }
    __builtin_amdgcn_s_setprio(0);
}

__global__ __launch_bounds__(512) void attn(
    const u16* __restrict__ Qb, const u16* __restrict__ Kb,
    const u16* __restrict__ Vt, u16* __restrict__ Ob)
{
    __shared__ __align__(16) u16 Kl[2][4096];
    __shared__ __align__(16) u16 Vl[2][4096];
    __shared__ __align__(16) u16 PlA[8][1024];
    __shared__ __align__(16) u16 PlB[8][1024];
    const int bh = blockIdx.y;
    const int b = bh >> 5, h = bh & 31;
    const int tid = threadIdx.x;
    const int wid = tid >> 6, lane = tid & 63;
    const int l15 = lane & 15, lg = lane >> 4;
    const int bxA = blockIdx.x, bxB = 15 - bxA;          // paired q-tiles
    const int q0A = bxA * 128 + wid * 16, q0B = bxB * 128 + wid * 16;
    const int qrowA = q0A + l15, qrowB = q0B + l15;
    char* prowA = (char*)PlA[wid] + l15 * 128;
    char* prowB = (char*)PlB[wid] + l15 * 128;
    const int psw = (l15 & 7) << 4;

    const u16* Kp = Kb + (size_t)bh * Ss * DHd;
    const u16* Vp = Vt + (size_t)bh * DHd * Ss;

    bf16x8 bqA[2], bqB[2];
    {
        const u16* QpA = Qb + ((size_t)bh * Ss + q0A) * DHd;
        const u16* QpB = Qb + ((size_t)bh * Ss + q0B) * DHd;
#pragma unroll
        for (int kf = 0; kf < 2; ++kf) {
            bqA[kf] = *(const bf16x8*)(QpA + (size_t)l15 * DHd + kf * 32 + lg * 8);
            bqB[kf] = *(const bf16x8*)(QpB + (size_t)l15 * DHd + kf * 32 + lg * 8);
        }
    }
    asm volatile("s_waitcnt vmcnt(0)" ::: "memory");   // drain Q loads: in-loop vmem = gld_lds only

    f32x4 oA[4] = {}, oB[4] = {};
    float mA = -3e38f, lA = 0.f, mB = -3e38f, lB = 0.f;
    const int nt = 2 * (bxB + 1);

    stage_kv(Kp, Vp, Kl[0], Vl[0], 0, tid);
    for (int t = 0; t < nt; ++t) {
        if (t + 1 < nt) {
            stage_kv(Kp, Vp, Kl[(t + 1) & 1], Vl[(t + 1) & 1], (t + 1) * 64, tid);
            asm volatile("s_waitcnt vmcnt(2)" ::: "memory");   // stage(t) landed (counted, no drain)
        } else {
            asm volatile("s_waitcnt vmcnt(0)" ::: "memory");
        }
        SB(); __builtin_amdgcn_s_barrier(); SB();
        const int kv0 = t * 64;
        attn_tile(Kl[t & 1], Vl[t & 1], kv0, q0A, qrowA, l15, lg, psw, bqA, oA, mA, lA, prowA);
        attn_tile(Kl[t & 1], Vl[t & 1], kv0, q0B, qrowB, l15, lg, psw, bqB, oB, mB, lB, prowB);
        SB(); __builtin_amdgcn_s_barrier(); SB();
    }

    {
        const float inv = 1.0f / lA;
        u16* orow = Ob + ((size_t)b * Ss + qrowA) * Dd + h * DHd;
#pragma unroll
        for (int nb = 0; nb < 4; ++nb) {
            u16x4 pk;
#pragma unroll
            for (int r = 0; r < 4; ++r) pk[r] = f2bf(oA[nb][r] * inv);
            *(u16x4*)(orow + nb * 16 + lg * 4) = pk;
        }
    }
    {
        const float inv = 1.0f / lB;
        u16* orow = Ob + ((size_t)b * Ss + qrowB) * Dd + h * DHd;
#pragma unroll
        for (int nb = 0; nb < 4; ++nb) {
            u16x4 pk;
#pragma unroll
            for (int r = 0; r < 4; ++r) pk[r] = f2bf(oB[nb][r] * inv);
            *(u16x4*)(orow + nb * 16 + lg * 4) = pk;
        }
    }
}

extern "C" void kernel_launch(void* const* d_in, const int* in_sizes, int n_in,
                              void* d_out, int out_size, void* d_ws, size_t ws_size,
                              hipStream_t stream)
{
    (void)in_sizes; (void)n_in; (void)out_size; (void)ws_size;
    const float* x  = (const float*)d_in[0];
    // d_in[1] = mask: causal, implemented directly
    const float* qw = (const float*)d_in[2];
    const float* qb = (const float*)d_in[3];
    const float* kw = (const float*)d_in[4];
    const float* kb = (const float*)d_in[5];
    const float* vw = (const float*)d_in[6];
    const float* vb = (const float*)d_in[7];
    const float* ow = (const float*)d_in[8];
    const float* obias = (const float*)d_in[9];

    uint8_t* ws = (uint8_t*)d_ws;
    u16* Xb  = (u16*)(ws);                 // 16 MiB [Mtok][Dd]
    u16* Wcat= (u16*)(ws + 16 * MiB);      // 24 MiB: Wq|Wk|Wv rows (6144 x 2048)
    u16* Wob = (u16*)(ws + 40 * MiB);      //  8 MiB
    u16* Qb  = (u16*)(ws + 48 * MiB);      // 16 MiB [BH][S][DH]
    u16* Kb  = (u16*)(ws + 64 * MiB);      // 16 MiB
    u16* Vb  = (u16*)(ws + 80 * MiB);      // 16 MiB
    u16* Vt  = Xb;                         // Xb dead after QKV gemms; [BH][DH][S]
    u16* Ob  = Vb;                         // Vb dead after transpose; attn out

    cvt_all<<<12288, 256, 0, stream>>>(x, qw, kw, vw, ow, Xb, Wcat, Wob);

    gemm_qkv8<<<dim3(Mtok / 128, 6144 / 256), dim3(512), 0, stream>>>(
        Xb, Wcat, qb, kb, vb, Qb, Kb, Vb);
    transpose_v<<<dim3(Ss / 64, 64), dim3(256), 0, stream>>>(Vb, Vt);
    attn<<<dim3(8, 64), dim3(512), 0, stream>>>(Qb, Kb, Vt, Ob);
    gemm_oproj8<<<dim3(Mtok / 128, Dd / 256), dim3(512), 0, stream>>>(
        Ob, Wob, obias, (float*)d_out);
}